// Round 1
// baseline (3676.417 us; speedup 1.0000x reference)
//
#include <hip/hip_runtime.h>

#define N_NODES 100000
#define N_EDGES 1600000
#define F_IN 256
#define F_HID 128
#define F_OUT 32

// ---------------- degree / norm ----------------
__global__ __launch_bounds__(256) void deg_kernel(const int* __restrict__ ei,
                                                  float* __restrict__ deg) {
    int e = blockIdx.x * 256 + threadIdx.x;
    if (e < N_EDGES) atomicAdd(&deg[ei[N_EDGES + e]], 1.0f);
}

__global__ __launch_bounds__(256) void dinv_kernel(float* __restrict__ deg) {
    int i = blockIdx.x * 256 + threadIdx.x;
    if (i < N_NODES) deg[i] = rsqrtf(deg[i] + 1.0f);  // self-loop => deg+1 >= 1
}

// ---------------- GEMM1: h0 = x @ W1   [100000,256]x[256,128] ----------------
__global__ __launch_bounds__(256) void gemm1_kernel(const float* __restrict__ x,
                                                    const float* __restrict__ W1,
                                                    float* __restrict__ h0) {
    __shared__ float As[64][32];    // A-tile reads are broadcast -> no pad needed
    __shared__ float Bs[32][128];
    const int tid = threadIdx.x;
    const int rbase = blockIdx.x * 64;
    const int tm = tid >> 5;   // 0..7  (8 rows each)
    const int tn = tid & 31;   // 0..31 (4 cols each)

    float acc[8][4];
#pragma unroll
    for (int i = 0; i < 8; i++)
#pragma unroll
        for (int j = 0; j < 4; j++) acc[i][j] = 0.f;

    for (int k0 = 0; k0 < F_IN; k0 += 32) {
        // A tile: 64x32 = 512 float4, 2 per thread
#pragma unroll
        for (int j = 0; j < 2; j++) {
            int f = tid * 2 + j;
            int row = f >> 3, c4 = f & 7;
            float4 v = make_float4(0.f, 0.f, 0.f, 0.f);
            int gr = rbase + row;
            if (gr < N_NODES) v = *(const float4*)(x + (size_t)gr * F_IN + k0 + c4 * 4);
            *(float4*)(&As[row][c4 * 4]) = v;
        }
        // B tile: 32x128 = 1024 float4, 4 per thread (coalesced)
#pragma unroll
        for (int j = 0; j < 4; j++) {
            int f = tid + 256 * j;
            int row = f >> 5, c4 = f & 31;
            *(float4*)(&Bs[row][c4 * 4]) = *(const float4*)(W1 + (size_t)(k0 + row) * F_HID + c4 * 4);
        }
        __syncthreads();
#pragma unroll
        for (int k = 0; k < 32; k++) {
            float4 b4 = *(const float4*)(&Bs[k][tn * 4]);
#pragma unroll
            for (int i = 0; i < 8; i++) {
                float a = As[tm * 8 + i][k];
                acc[i][0] += a * b4.x;
                acc[i][1] += a * b4.y;
                acc[i][2] += a * b4.z;
                acc[i][3] += a * b4.w;
            }
        }
        __syncthreads();
    }
#pragma unroll
    for (int i = 0; i < 8; i++) {
        int r = rbase + tm * 8 + i;
        if (r < N_NODES) {
            float4 v = make_float4(acc[i][0], acc[i][1], acc[i][2], acc[i][3]);
            *(float4*)(h0 + (size_t)r * F_HID + tn * 4) = v;
        }
    }
}

// ---------------- aggregation layer 1 ----------------
// init: agg[i,:] = h0[i,:] * dinv[i]^2   (self-loop term, also zero-initializes)
__global__ __launch_bounds__(256) void init_agg128(const float* __restrict__ h0,
                                                   const float* __restrict__ dinv,
                                                   float* __restrict__ agg) {
    int idx = blockIdx.x * 256 + threadIdx.x;  // one float4; total 3.2M
    int node = idx >> 5;                       // 32 float4 per row
    float s = dinv[node];
    s *= s;
    float4 v = ((const float4*)h0)[idx];
    v.x *= s; v.y *= s; v.z *= s; v.w *= s;
    ((float4*)agg)[idx] = v;
}

// per-edge scatter: half-wave (32 lanes) per edge, float4 per lane
__global__ __launch_bounds__(256) void scatter128(const float* __restrict__ h0,
                                                  const int* __restrict__ ei,
                                                  const float* __restrict__ dinv,
                                                  float* __restrict__ agg) {
    int e = blockIdx.x * 8 + (threadIdx.x >> 5);  // 8 half-waves per block
    int l = threadIdx.x & 31;
    int src = ei[e];
    int dst = ei[N_EDGES + e];
    float nrm = dinv[src] * dinv[dst];
    float4 v = ((const float4*)(h0 + (size_t)src * F_HID))[l];
    float* o = agg + (size_t)dst * F_HID + l * 4;
    atomicAdd(o + 0, v.x * nrm);
    atomicAdd(o + 1, v.y * nrm);
    atomicAdd(o + 2, v.z * nrm);
    atomicAdd(o + 3, v.w * nrm);
}

// ---------------- GEMM2: h2 = relu(agg + b1) @ W2   [100000,128]x[128,32] ----------------
__global__ __launch_bounds__(256) void gemm2_kernel(const float* __restrict__ agg,
                                                    const float* __restrict__ b1,
                                                    const float* __restrict__ W2,
                                                    float* __restrict__ h2) {
    __shared__ float Ws[F_HID * F_OUT];  // 16 KB, whole W2
    __shared__ float As[64][F_HID + 1];  // +1 pad: breaks 16-way bank alias on a-reads
    __shared__ float b1s[F_HID];
    const int tid = threadIdx.x;
    const int rbase = blockIdx.x * 64;

    if (tid < F_HID) b1s[tid] = b1[tid];
#pragma unroll
    for (int j = 0; j < 4; j++) {
        int f = tid + 256 * j;  // 1024 float4 = whole W2
        ((float4*)Ws)[f] = ((const float4*)W2)[f];
    }
    __syncthreads();

    // A tile with fused bias+relu: 64x128 = 2048 float4, 8 per thread
#pragma unroll
    for (int j = 0; j < 8; j++) {
        int f = tid + 256 * j;
        int row = f >> 5, c4 = f & 31;
        int gr = rbase + row;
        float4 v = make_float4(0.f, 0.f, 0.f, 0.f);
        if (gr < N_NODES) v = *(const float4*)(agg + (size_t)gr * F_HID + c4 * 4);
        int c = c4 * 4;
        As[row][c + 0] = fmaxf(v.x + b1s[c + 0], 0.f);
        As[row][c + 1] = fmaxf(v.y + b1s[c + 1], 0.f);
        As[row][c + 2] = fmaxf(v.z + b1s[c + 2], 0.f);
        As[row][c + 3] = fmaxf(v.w + b1s[c + 3], 0.f);
    }
    __syncthreads();

    const int r = tid >> 2;          // 0..63
    const int c0 = (tid & 3) * 8;    // 0,8,16,24
    float acc[8] = {0, 0, 0, 0, 0, 0, 0, 0};
#pragma unroll 4
    for (int k = 0; k < F_HID; k++) {
        float a = As[r][k];
#pragma unroll
        for (int j = 0; j < 8; j++) acc[j] += a * Ws[k * F_OUT + c0 + j];
    }
    int gr = rbase + r;
    if (gr < N_NODES) {
        *(float4*)(h2 + (size_t)gr * F_OUT + c0)     = make_float4(acc[0], acc[1], acc[2], acc[3]);
        *(float4*)(h2 + (size_t)gr * F_OUT + c0 + 4) = make_float4(acc[4], acc[5], acc[6], acc[7]);
    }
}

// ---------------- aggregation layer 2 ----------------
__global__ __launch_bounds__(256) void init_agg32(const float* __restrict__ h2,
                                                  const float* __restrict__ dinv,
                                                  float* __restrict__ agg2) {
    int idx = blockIdx.x * 256 + threadIdx.x;  // one float4; total 800000
    int node = idx >> 3;                       // 8 float4 per row
    float s = dinv[node];
    s *= s;
    float4 v = ((const float4*)h2)[idx];
    v.x *= s; v.y *= s; v.z *= s; v.w *= s;
    ((float4*)agg2)[idx] = v;
}

__global__ __launch_bounds__(256) void scatter32(const float* __restrict__ h2,
                                                 const int* __restrict__ ei,
                                                 const float* __restrict__ dinv,
                                                 float* __restrict__ agg2) {
    int e = blockIdx.x * 32 + (threadIdx.x >> 3);  // 8 lanes per edge
    int l = threadIdx.x & 7;
    int src = ei[e];
    int dst = ei[N_EDGES + e];
    float nrm = dinv[src] * dinv[dst];
    float4 v = ((const float4*)(h2 + (size_t)src * F_OUT))[l];
    float* o = agg2 + (size_t)dst * F_OUT + l * 4;
    atomicAdd(o + 0, v.x * nrm);
    atomicAdd(o + 1, v.y * nrm);
    atomicAdd(o + 2, v.z * nrm);
    atomicAdd(o + 3, v.w * nrm);
}

// ---------------- bias + log_softmax ----------------
__global__ __launch_bounds__(256) void lsm_kernel(const float* __restrict__ agg2,
                                                  const float* __restrict__ b2,
                                                  float* __restrict__ out) {
    int row = blockIdx.x * 8 + (threadIdx.x >> 5);  // 8 rows per block
    int l = threadIdx.x & 31;
    float v = agg2[(size_t)row * F_OUT + l] + b2[l];
    float m = v;
#pragma unroll
    for (int off = 16; off; off >>= 1) m = fmaxf(m, __shfl_xor(m, off, 32));
    float ex = __expf(v - m);
    float s = ex;
#pragma unroll
    for (int off = 16; off; off >>= 1) s += __shfl_xor(s, off, 32);
    out[(size_t)row * F_OUT + l] = (v - m) - __logf(s);
}

extern "C" void kernel_launch(void* const* d_in, const int* in_sizes, int n_in,
                              void* d_out, int out_size, void* d_ws, size_t ws_size,
                              hipStream_t stream) {
    const float* x  = (const float*)d_in[0];
    const int*   ei = (const int*)d_in[1];
    const float* W1 = (const float*)d_in[2];
    const float* b1 = (const float*)d_in[3];
    const float* W2 = (const float*)d_in[4];
    const float* b2 = (const float*)d_in[5];
    float* out = (float*)d_out;

    float* ws   = (float*)d_ws;
    float* dinv = ws;                       // 100000 (padded to 102400)
    float* h0   = ws + 102400;              // 100000*128 = 12.8M
    float* agg  = h0 + 12800000;            // 12.8M
    float* h2   = agg + 12800000;           // 100000*32 = 3.2M
    float* agg2 = h0;                       // alias: h0 dead after scatter128

    hipMemsetAsync(dinv, 0, N_NODES * sizeof(float), stream);
    deg_kernel<<<N_EDGES / 256, 256, 0, stream>>>(ei, dinv);
    dinv_kernel<<<(N_NODES + 255) / 256, 256, 0, stream>>>(dinv);
    gemm1_kernel<<<(N_NODES + 63) / 64, 256, 0, stream>>>(x, W1, h0);
    init_agg128<<<N_NODES * 32 / 256, 256, 0, stream>>>(h0, dinv, agg);
    scatter128<<<N_EDGES / 8, 256, 0, stream>>>(h0, ei, dinv, agg);
    gemm2_kernel<<<(N_NODES + 63) / 64, 256, 0, stream>>>(agg, b1, W2, h2);
    init_agg32<<<N_NODES * 8 / 256, 256, 0, stream>>>(h2, dinv, agg2);
    scatter32<<<N_EDGES / 32, 256, 0, stream>>>(h2, ei, dinv, agg2);
    lsm_kernel<<<(N_NODES + 7) / 8, 256, 0, stream>>>(agg2, b2, out);
}

// Round 2
// 610.131 us; speedup vs baseline: 6.0256x; 6.0256x over previous
//
#include <hip/hip_runtime.h>

#define N_NODES 100000
#define N_EDGES 1600000
#define F_IN 256
#define F_HID 128
#define F_OUT 32
#define NB1 391   // ceil(100000/256)

// ---------------- degree ----------------
__global__ __launch_bounds__(256) void deg_kernel(const int* __restrict__ ei,
                                                  float* __restrict__ deg) {
    int e = blockIdx.x * 256 + threadIdx.x;
    if (e < N_EDGES) atomicAdd(&deg[ei[N_EDGES + e]], 1.0f);
}

// ---------------- CSR build: scan of degrees ----------------
__global__ __launch_bounds__(256) void blocksum_kernel(const float* __restrict__ deg,
                                                       int* __restrict__ bsum) {
    __shared__ int s[256];
    int i = blockIdx.x * 256 + threadIdx.x;
    s[threadIdx.x] = (i < N_NODES) ? (int)deg[i] : 0;
    __syncthreads();
    for (int off = 128; off; off >>= 1) {
        if (threadIdx.x < off) s[threadIdx.x] += s[threadIdx.x + off];
        __syncthreads();
    }
    if (threadIdx.x == 0) bsum[blockIdx.x] = s[0];
}

__global__ __launch_bounds__(512) void scan_bsums(const int* __restrict__ bsum,
                                                  int* __restrict__ boff,
                                                  int* __restrict__ offs) {
    __shared__ int s[512];
    int t = threadIdx.x;
    int own = (t < NB1) ? bsum[t] : 0;
    s[t] = own;
    __syncthreads();
    for (int off = 1; off < 512; off <<= 1) {
        int v = (t >= off) ? s[t - off] : 0;
        __syncthreads();
        s[t] += v;
        __syncthreads();
    }
    if (t < NB1) boff[t] = s[t] - own;  // exclusive
    if (t == 0) offs[N_NODES] = N_EDGES;
}

__global__ __launch_bounds__(256) void scatter_offs(const float* __restrict__ deg,
                                                    const int* __restrict__ boff,
                                                    int* __restrict__ offs,
                                                    int* __restrict__ cursor) {
    __shared__ int s[256];
    int t = threadIdx.x;
    int i = blockIdx.x * 256 + t;
    int d = (i < N_NODES) ? (int)deg[i] : 0;
    s[t] = d;
    __syncthreads();
    for (int off = 1; off < 256; off <<= 1) {
        int v = (t >= off) ? s[t - off] : 0;
        __syncthreads();
        s[t] += v;
        __syncthreads();
    }
    if (i < N_NODES) {
        int o = boff[blockIdx.x] + s[t] - d;
        offs[i] = o;
        cursor[i] = o;
    }
}

__global__ __launch_bounds__(256) void dinv_kernel(float* __restrict__ deg) {
    int i = blockIdx.x * 256 + threadIdx.x;
    if (i < N_NODES) deg[i] = rsqrtf(deg[i] + 1.0f);  // self-loop => deg+1 >= 1
}

__global__ __launch_bounds__(256) void fill_kernel(const int* __restrict__ ei,
                                                   int* __restrict__ cursor,
                                                   int* __restrict__ csr) {
    int e = blockIdx.x * 256 + threadIdx.x;
    if (e < N_EDGES) {
        int src = ei[e];
        int dst = ei[N_EDGES + e];
        int pos = atomicAdd(&cursor[dst], 1);
        csr[pos] = src;
    }
}

// ---------------- GEMM1: h0 = x @ W1   [100000,256]x[256,128] ----------------
__global__ __launch_bounds__(256) void gemm1_kernel(const float* __restrict__ x,
                                                    const float* __restrict__ W1,
                                                    float* __restrict__ h0) {
    __shared__ float As[64][32];
    __shared__ float Bs[32][128];
    const int tid = threadIdx.x;
    const int rbase = blockIdx.x * 64;
    const int tm = tid >> 5;
    const int tn = tid & 31;

    float acc[8][4];
#pragma unroll
    for (int i = 0; i < 8; i++)
#pragma unroll
        for (int j = 0; j < 4; j++) acc[i][j] = 0.f;

    for (int k0 = 0; k0 < F_IN; k0 += 32) {
#pragma unroll
        for (int j = 0; j < 2; j++) {
            int f = tid * 2 + j;
            int row = f >> 3, c4 = f & 7;
            float4 v = make_float4(0.f, 0.f, 0.f, 0.f);
            int gr = rbase + row;
            if (gr < N_NODES) v = *(const float4*)(x + (size_t)gr * F_IN + k0 + c4 * 4);
            *(float4*)(&As[row][c4 * 4]) = v;
        }
#pragma unroll
        for (int j = 0; j < 4; j++) {
            int f = tid + 256 * j;
            int row = f >> 5, c4 = f & 31;
            *(float4*)(&Bs[row][c4 * 4]) = *(const float4*)(W1 + (size_t)(k0 + row) * F_HID + c4 * 4);
        }
        __syncthreads();
#pragma unroll
        for (int k = 0; k < 32; k++) {
            float4 b4 = *(const float4*)(&Bs[k][tn * 4]);
#pragma unroll
            for (int i = 0; i < 8; i++) {
                float a = As[tm * 8 + i][k];
                acc[i][0] += a * b4.x;
                acc[i][1] += a * b4.y;
                acc[i][2] += a * b4.z;
                acc[i][3] += a * b4.w;
            }
        }
        __syncthreads();
    }
#pragma unroll
    for (int i = 0; i < 8; i++) {
        int r = rbase + tm * 8 + i;
        if (r < N_NODES) {
            float4 v = make_float4(acc[i][0], acc[i][1], acc[i][2], acc[i][3]);
            *(float4*)(h0 + (size_t)r * F_HID + tn * 4) = v;
        }
    }
}

// ---------------- gather aggregation layer 1 (fused self-loop) ----------------
// agg[n,:] = dinv[n]^2 * h0[n,:] + sum_{e: dst=n} dinv[src]*dinv[n] * h0[src,:]
__global__ __launch_bounds__(256) void gather128(const float* __restrict__ h0,
                                                 const int* __restrict__ offs,
                                                 const int* __restrict__ csr,
                                                 const float* __restrict__ dinv,
                                                 float* __restrict__ agg) {
    int node = blockIdx.x * 8 + (threadIdx.x >> 5);  // 8 half-waves/block
    int l = threadIdx.x & 31;
    float dn = dinv[node];
    float4 acc = ((const float4*)(h0 + (size_t)node * F_HID))[l];
    float s = dn * dn;
    acc.x *= s; acc.y *= s; acc.z *= s; acc.w *= s;

    int beg = offs[node], end = offs[node + 1];
    int j = beg;
    for (; j + 1 < end; j += 2) {
        int s0 = csr[j], s1 = csr[j + 1];
        float n0 = dinv[s0] * dn, n1 = dinv[s1] * dn;
        float4 v0 = ((const float4*)(h0 + (size_t)s0 * F_HID))[l];
        float4 v1 = ((const float4*)(h0 + (size_t)s1 * F_HID))[l];
        acc.x += v0.x * n0 + v1.x * n1;
        acc.y += v0.y * n0 + v1.y * n1;
        acc.z += v0.z * n0 + v1.z * n1;
        acc.w += v0.w * n0 + v1.w * n1;
    }
    if (j < end) {
        int s0 = csr[j];
        float n0 = dinv[s0] * dn;
        float4 v0 = ((const float4*)(h0 + (size_t)s0 * F_HID))[l];
        acc.x += v0.x * n0; acc.y += v0.y * n0; acc.z += v0.z * n0; acc.w += v0.w * n0;
    }
    ((float4*)(agg + (size_t)node * F_HID))[l] = acc;
}

// ---------------- GEMM2: h2 = relu(agg + b1) @ W2 ----------------
__global__ __launch_bounds__(256) void gemm2_kernel(const float* __restrict__ agg,
                                                    const float* __restrict__ b1,
                                                    const float* __restrict__ W2,
                                                    float* __restrict__ h2) {
    __shared__ float Ws[F_HID * F_OUT];
    __shared__ float As[64][F_HID + 1];
    __shared__ float b1s[F_HID];
    const int tid = threadIdx.x;
    const int rbase = blockIdx.x * 64;

    if (tid < F_HID) b1s[tid] = b1[tid];
#pragma unroll
    for (int j = 0; j < 4; j++) {
        int f = tid + 256 * j;
        ((float4*)Ws)[f] = ((const float4*)W2)[f];
    }
    __syncthreads();

#pragma unroll
    for (int j = 0; j < 8; j++) {
        int f = tid + 256 * j;
        int row = f >> 5, c4 = f & 31;
        int gr = rbase + row;
        float4 v = make_float4(0.f, 0.f, 0.f, 0.f);
        if (gr < N_NODES) v = *(const float4*)(agg + (size_t)gr * F_HID + c4 * 4);
        int c = c4 * 4;
        As[row][c + 0] = fmaxf(v.x + b1s[c + 0], 0.f);
        As[row][c + 1] = fmaxf(v.y + b1s[c + 1], 0.f);
        As[row][c + 2] = fmaxf(v.z + b1s[c + 2], 0.f);
        As[row][c + 3] = fmaxf(v.w + b1s[c + 3], 0.f);
    }
    __syncthreads();

    const int r = tid >> 2;
    const int c0 = (tid & 3) * 8;
    float acc[8] = {0, 0, 0, 0, 0, 0, 0, 0};
#pragma unroll 4
    for (int k = 0; k < F_HID; k++) {
        float a = As[r][k];
#pragma unroll
        for (int j = 0; j < 8; j++) acc[j] += a * Ws[k * F_OUT + c0 + j];
    }
    int gr = rbase + r;
    if (gr < N_NODES) {
        *(float4*)(h2 + (size_t)gr * F_OUT + c0)     = make_float4(acc[0], acc[1], acc[2], acc[3]);
        *(float4*)(h2 + (size_t)gr * F_OUT + c0 + 4) = make_float4(acc[4], acc[5], acc[6], acc[7]);
    }
}

// ---------------- gather aggregation layer 2 + bias + log_softmax ----------------
__global__ __launch_bounds__(256) void gather32_lsm(const float* __restrict__ h2,
                                                    const int* __restrict__ offs,
                                                    const int* __restrict__ csr,
                                                    const float* __restrict__ dinv,
                                                    const float* __restrict__ b2,
                                                    float* __restrict__ out) {
    int node = blockIdx.x * 32 + (threadIdx.x >> 3);  // 8 lanes/node
    int l = threadIdx.x & 7;
    float dn = dinv[node];
    float4 acc = ((const float4*)(h2 + (size_t)node * F_OUT))[l];
    float s = dn * dn;
    acc.x *= s; acc.y *= s; acc.z *= s; acc.w *= s;

    int beg = offs[node], end = offs[node + 1];
    int j = beg;
    for (; j + 1 < end; j += 2) {
        int s0 = csr[j], s1 = csr[j + 1];
        float n0 = dinv[s0] * dn, n1 = dinv[s1] * dn;
        float4 v0 = ((const float4*)(h2 + (size_t)s0 * F_OUT))[l];
        float4 v1 = ((const float4*)(h2 + (size_t)s1 * F_OUT))[l];
        acc.x += v0.x * n0 + v1.x * n1;
        acc.y += v0.y * n0 + v1.y * n1;
        acc.z += v0.z * n0 + v1.z * n1;
        acc.w += v0.w * n0 + v1.w * n1;
    }
    if (j < end) {
        int s0 = csr[j];
        float n0 = dinv[s0] * dn;
        float4 v0 = ((const float4*)(h2 + (size_t)s0 * F_OUT))[l];
        acc.x += v0.x * n0; acc.y += v0.y * n0; acc.z += v0.z * n0; acc.w += v0.w * n0;
    }
    float4 bb = ((const float4*)b2)[l];
    acc.x += bb.x; acc.y += bb.y; acc.z += bb.z; acc.w += bb.w;

    // log-softmax over the 32 values spread across 8 lanes x 4
    float m = fmaxf(fmaxf(acc.x, acc.y), fmaxf(acc.z, acc.w));
#pragma unroll
    for (int off = 1; off < 8; off <<= 1) m = fmaxf(m, __shfl_xor(m, off, 8));
    float es = __expf(acc.x - m) + __expf(acc.y - m) + __expf(acc.z - m) + __expf(acc.w - m);
#pragma unroll
    for (int off = 1; off < 8; off <<= 1) es += __shfl_xor(es, off, 8);
    float lse = m + __logf(es);
    float4 o = make_float4(acc.x - lse, acc.y - lse, acc.z - lse, acc.w - lse);
    ((float4*)(out + (size_t)node * F_OUT))[l] = o;
}

extern "C" void kernel_launch(void* const* d_in, const int* in_sizes, int n_in,
                              void* d_out, int out_size, void* d_ws, size_t ws_size,
                              hipStream_t stream) {
    const float* x  = (const float*)d_in[0];
    const int*   ei = (const int*)d_in[1];
    const float* W1 = (const float*)d_in[2];
    const float* b1 = (const float*)d_in[3];
    const float* W2 = (const float*)d_in[4];
    const float* b2 = (const float*)d_in[5];
    float* out = (float*)d_out;

    float* ws   = (float*)d_ws;
    float* dinv   = ws;                            // 102400 floats (deg -> dinv)
    int*   offs   = (int*)(ws + 102400);           // 100001 ints (reserve 102656)
    int*   cursor = offs + 102656;                 // 102400
    int*   bsum   = cursor + 102400;               // 512
    int*   boff   = bsum + 512;                    // 512
    int*   csr    = boff + 512;                    // 1,600,000
    float* h0     = (float*)(csr + 1600000);       // 12.8M
    float* agg    = h0 + 12800000;                 // 12.8M
    float* h2     = h0;                            // alias: h0 dead after gather128

    hipMemsetAsync(dinv, 0, N_NODES * sizeof(float), stream);
    deg_kernel<<<N_EDGES / 256, 256, 0, stream>>>(ei, dinv);
    blocksum_kernel<<<NB1, 256, 0, stream>>>(dinv, bsum);
    scan_bsums<<<1, 512, 0, stream>>>(bsum, boff, offs);
    scatter_offs<<<NB1, 256, 0, stream>>>(dinv, boff, offs, cursor);
    dinv_kernel<<<NB1, 256, 0, stream>>>(dinv);
    fill_kernel<<<N_EDGES / 256, 256, 0, stream>>>(ei, cursor, csr);
    gemm1_kernel<<<(N_NODES + 63) / 64, 256, 0, stream>>>(x, W1, h0);
    gather128<<<N_NODES / 8, 256, 0, stream>>>(h0, offs, csr, dinv, agg);
    gemm2_kernel<<<(N_NODES + 63) / 64, 256, 0, stream>>>(agg, b1, W2, h2);
    gather32_lsm<<<N_NODES / 32, 256, 0, stream>>>(h2, offs, csr, dinv, b2, out);
}

// Round 3
// 485.247 us; speedup vs baseline: 7.5764x; 1.2574x over previous
//
#include <hip/hip_runtime.h>

#define N_NODES 100000
#define N_EDGES 1600000
#define F_IN 256
#define F_HID 128
#define F_OUT 32
#define NBUCK 391           // ceil(100000/256) buckets of 256 node ids
#define BIN_BLOCKS 512
#define EDGES_PER_BIN 3125  // 512*3125 = 1,600,000

// ---------------- CSR build, pass 1: coarse histogram ----------------
__global__ __launch_bounds__(256) void hist_kernel(const int* __restrict__ ei,
                                                   int* __restrict__ bucket_cnt) {
    __shared__ int h[NBUCK];
    for (int i = threadIdx.x; i < NBUCK; i += 256) h[i] = 0;
    __syncthreads();
    int gid = blockIdx.x * 256 + threadIdx.x;
    for (int e = gid; e < N_EDGES; e += BIN_BLOCKS * 256)
        atomicAdd(&h[ei[N_EDGES + e] >> 8], 1);
    __syncthreads();
    for (int i = threadIdx.x; i < NBUCK; i += 256) {
        int c = h[i];
        if (c) atomicAdd(&bucket_cnt[i], c);
    }
}

// ---------------- CSR build: scan bucket counts ----------------
__global__ __launch_bounds__(512) void scan_kernel(const int* __restrict__ bucket_cnt,
                                                   int* __restrict__ bucket_base,
                                                   int* __restrict__ bucket_cursor,
                                                   int* __restrict__ offs) {
    __shared__ int s[512];
    int t = threadIdx.x;
    int own = (t < NBUCK) ? bucket_cnt[t] : 0;
    s[t] = own;
    __syncthreads();
    for (int off = 1; off < 512; off <<= 1) {
        int v = (t >= off) ? s[t - off] : 0;
        __syncthreads();
        s[t] += v;
        __syncthreads();
    }
    if (t < NBUCK) {
        int ex = s[t] - own;
        bucket_base[t] = ex;
        bucket_cursor[t] = ex;
    }
    if (t == 0) {
        bucket_base[NBUCK] = N_EDGES;
        offs[N_NODES] = N_EDGES;
    }
}

// ---------------- CSR build, pass 2: bin edges into bucket regions ----------------
__global__ __launch_bounds__(256) void bin_kernel(const int* __restrict__ ei,
                                                  int* __restrict__ bucket_cursor,
                                                  int2* __restrict__ binned) {
    __shared__ int h[NBUCK];
    __shared__ int base[NBUCK];
    const int t = threadIdx.x;
    const int beg = blockIdx.x * EDGES_PER_BIN;
    const int end = beg + EDGES_PER_BIN;
    for (int i = t; i < NBUCK; i += 256) h[i] = 0;
    __syncthreads();
    for (int e = beg + t; e < end; e += 256) atomicAdd(&h[ei[N_EDGES + e] >> 8], 1);
    __syncthreads();
    for (int i = t; i < NBUCK; i += 256) {
        int c = h[i];
        base[i] = c ? atomicAdd(&bucket_cursor[i], c) : 0;
        h[i] = 0;
    }
    __syncthreads();
    for (int e = beg + t; e < end; e += 256) {
        int s = ei[e], d = ei[N_EDGES + e];
        int bk = d >> 8;
        int p = base[bk] + atomicAdd(&h[bk], 1);
        binned[p] = make_int2(s, d);
    }
}

// ---------------- CSR build, pass 3: per-bucket offs/dinv/csr ----------------
__global__ __launch_bounds__(256) void build_kernel(const int2* __restrict__ binned,
                                                    const int* __restrict__ bucket_base,
                                                    int* __restrict__ offs,
                                                    int* __restrict__ csr,
                                                    float* __restrict__ dinv) {
    __shared__ int h[256];
    __shared__ int sc[256];
    __shared__ int cur[256];
    const int b = blockIdx.x, t = threadIdx.x;
    const int beg = bucket_base[b];
    const int end = bucket_base[b + 1];
    h[t] = 0;
    __syncthreads();
    for (int j = beg + t; j < end; j += 256) {
        int2 p = binned[j];
        atomicAdd(&h[p.y & 255], 1);
    }
    __syncthreads();
    int deg = h[t];
    sc[t] = deg;
    __syncthreads();
    for (int off = 1; off < 256; off <<= 1) {
        int v = (t >= off) ? sc[t - off] : 0;
        __syncthreads();
        sc[t] += v;
        __syncthreads();
    }
    int excl = sc[t] - deg;
    cur[t] = excl;
    int node = b * 256 + t;
    if (node < N_NODES) {
        offs[node] = beg + excl;
        dinv[node] = rsqrtf((float)deg + 1.0f);  // +1 self-loop
    }
    __syncthreads();
    for (int j = beg + t; j < end; j += 256) {
        int2 p = binned[j];
        int pos = atomicAdd(&cur[p.y & 255], 1);
        csr[beg + pos] = p.x;
    }
}

// ---------------- GEMM1: h0 = x @ W1   [100000,256]x[256,128] ----------------
__global__ __launch_bounds__(256) void gemm1_kernel(const float* __restrict__ x,
                                                    const float* __restrict__ W1,
                                                    float* __restrict__ h0) {
    __shared__ float As[64][32];
    __shared__ float Bs[32][128];
    const int tid = threadIdx.x;
    const int rbase = blockIdx.x * 64;
    const int tm = tid >> 5;
    const int tn = tid & 31;

    float acc[8][4];
#pragma unroll
    for (int i = 0; i < 8; i++)
#pragma unroll
        for (int j = 0; j < 4; j++) acc[i][j] = 0.f;

    for (int k0 = 0; k0 < F_IN; k0 += 32) {
#pragma unroll
        for (int j = 0; j < 2; j++) {
            int f = tid * 2 + j;
            int row = f >> 3, c4 = f & 7;
            float4 v = make_float4(0.f, 0.f, 0.f, 0.f);
            int gr = rbase + row;
            if (gr < N_NODES) v = *(const float4*)(x + (size_t)gr * F_IN + k0 + c4 * 4);
            *(float4*)(&As[row][c4 * 4]) = v;
        }
#pragma unroll
        for (int j = 0; j < 4; j++) {
            int f = tid + 256 * j;
            int row = f >> 5, c4 = f & 31;
            *(float4*)(&Bs[row][c4 * 4]) = *(const float4*)(W1 + (size_t)(k0 + row) * F_HID + c4 * 4);
        }
        __syncthreads();
#pragma unroll
        for (int k = 0; k < 32; k++) {
            float4 b4 = *(const float4*)(&Bs[k][tn * 4]);
#pragma unroll
            for (int i = 0; i < 8; i++) {
                float a = As[tm * 8 + i][k];
                acc[i][0] += a * b4.x;
                acc[i][1] += a * b4.y;
                acc[i][2] += a * b4.z;
                acc[i][3] += a * b4.w;
            }
        }
        __syncthreads();
    }
#pragma unroll
    for (int i = 0; i < 8; i++) {
        int r = rbase + tm * 8 + i;
        if (r < N_NODES) {
            float4 v = make_float4(acc[i][0], acc[i][1], acc[i][2], acc[i][3]);
            *(float4*)(h0 + (size_t)r * F_HID + tn * 4) = v;
        }
    }
}

// ---------------- gather aggregation layer 1 (fused self-loop) ----------------
__global__ __launch_bounds__(256) void gather128(const float* __restrict__ h0,
                                                 const int* __restrict__ offs,
                                                 const int* __restrict__ csr,
                                                 const float* __restrict__ dinv,
                                                 float* __restrict__ agg) {
    int node = blockIdx.x * 8 + (threadIdx.x >> 5);
    int l = threadIdx.x & 31;
    float dn = dinv[node];
    float4 acc = ((const float4*)(h0 + (size_t)node * F_HID))[l];
    float s = dn * dn;
    acc.x *= s; acc.y *= s; acc.z *= s; acc.w *= s;

    int beg = offs[node], end = offs[node + 1];
    int j = beg;
    for (; j + 1 < end; j += 2) {
        int s0 = csr[j], s1 = csr[j + 1];
        float n0 = dinv[s0] * dn, n1 = dinv[s1] * dn;
        float4 v0 = ((const float4*)(h0 + (size_t)s0 * F_HID))[l];
        float4 v1 = ((const float4*)(h0 + (size_t)s1 * F_HID))[l];
        acc.x += v0.x * n0 + v1.x * n1;
        acc.y += v0.y * n0 + v1.y * n1;
        acc.z += v0.z * n0 + v1.z * n1;
        acc.w += v0.w * n0 + v1.w * n1;
    }
    if (j < end) {
        int s0 = csr[j];
        float n0 = dinv[s0] * dn;
        float4 v0 = ((const float4*)(h0 + (size_t)s0 * F_HID))[l];
        acc.x += v0.x * n0; acc.y += v0.y * n0; acc.z += v0.z * n0; acc.w += v0.w * n0;
    }
    ((float4*)(agg + (size_t)node * F_HID))[l] = acc;
}

// ---------------- GEMM2: h2 = relu(agg + b1) @ W2 ----------------
__global__ __launch_bounds__(256) void gemm2_kernel(const float* __restrict__ agg,
                                                    const float* __restrict__ b1,
                                                    const float* __restrict__ W2,
                                                    float* __restrict__ h2) {
    __shared__ float Ws[F_HID * F_OUT];
    __shared__ float As[64][F_HID + 1];
    __shared__ float b1s[F_HID];
    const int tid = threadIdx.x;
    const int rbase = blockIdx.x * 64;

    if (tid < F_HID) b1s[tid] = b1[tid];
#pragma unroll
    for (int j = 0; j < 4; j++) {
        int f = tid + 256 * j;
        ((float4*)Ws)[f] = ((const float4*)W2)[f];
    }
    __syncthreads();

#pragma unroll
    for (int j = 0; j < 8; j++) {
        int f = tid + 256 * j;
        int row = f >> 5, c4 = f & 31;
        int gr = rbase + row;
        float4 v = make_float4(0.f, 0.f, 0.f, 0.f);
        if (gr < N_NODES) v = *(const float4*)(agg + (size_t)gr * F_HID + c4 * 4);
        int c = c4 * 4;
        As[row][c + 0] = fmaxf(v.x + b1s[c + 0], 0.f);
        As[row][c + 1] = fmaxf(v.y + b1s[c + 1], 0.f);
        As[row][c + 2] = fmaxf(v.z + b1s[c + 2], 0.f);
        As[row][c + 3] = fmaxf(v.w + b1s[c + 3], 0.f);
    }
    __syncthreads();

    const int r = tid >> 2;
    const int c0 = (tid & 3) * 8;
    float acc[8] = {0, 0, 0, 0, 0, 0, 0, 0};
#pragma unroll 4
    for (int k = 0; k < F_HID; k++) {
        float a = As[r][k];
#pragma unroll
        for (int j = 0; j < 8; j++) acc[j] += a * Ws[k * F_OUT + c0 + j];
    }
    int gr = rbase + r;
    if (gr < N_NODES) {
        *(float4*)(h2 + (size_t)gr * F_OUT + c0)     = make_float4(acc[0], acc[1], acc[2], acc[3]);
        *(float4*)(h2 + (size_t)gr * F_OUT + c0 + 4) = make_float4(acc[4], acc[5], acc[6], acc[7]);
    }
}

// ---------------- gather aggregation layer 2 + bias + log_softmax ----------------
__global__ __launch_bounds__(256) void gather32_lsm(const float* __restrict__ h2,
                                                    const int* __restrict__ offs,
                                                    const int* __restrict__ csr,
                                                    const float* __restrict__ dinv,
                                                    const float* __restrict__ b2,
                                                    float* __restrict__ out) {
    int node = blockIdx.x * 32 + (threadIdx.x >> 3);
    int l = threadIdx.x & 7;
    float dn = dinv[node];
    float4 acc = ((const float4*)(h2 + (size_t)node * F_OUT))[l];
    float s = dn * dn;
    acc.x *= s; acc.y *= s; acc.z *= s; acc.w *= s;

    int beg = offs[node], end = offs[node + 1];
    int j = beg;
    for (; j + 1 < end; j += 2) {
        int s0 = csr[j], s1 = csr[j + 1];
        float n0 = dinv[s0] * dn, n1 = dinv[s1] * dn;
        float4 v0 = ((const float4*)(h2 + (size_t)s0 * F_OUT))[l];
        float4 v1 = ((const float4*)(h2 + (size_t)s1 * F_OUT))[l];
        acc.x += v0.x * n0 + v1.x * n1;
        acc.y += v0.y * n0 + v1.y * n1;
        acc.z += v0.z * n0 + v1.z * n1;
        acc.w += v0.w * n0 + v1.w * n1;
    }
    if (j < end) {
        int s0 = csr[j];
        float n0 = dinv[s0] * dn;
        float4 v0 = ((const float4*)(h2 + (size_t)s0 * F_OUT))[l];
        acc.x += v0.x * n0; acc.y += v0.y * n0; acc.z += v0.z * n0; acc.w += v0.w * n0;
    }
    float4 bb = ((const float4*)b2)[l];
    acc.x += bb.x; acc.y += bb.y; acc.z += bb.z; acc.w += bb.w;

    float m = fmaxf(fmaxf(acc.x, acc.y), fmaxf(acc.z, acc.w));
#pragma unroll
    for (int off = 1; off < 8; off <<= 1) m = fmaxf(m, __shfl_xor(m, off, 8));
    float es = __expf(acc.x - m) + __expf(acc.y - m) + __expf(acc.z - m) + __expf(acc.w - m);
#pragma unroll
    for (int off = 1; off < 8; off <<= 1) es += __shfl_xor(es, off, 8);
    float lse = m + __logf(es);
    float4 o = make_float4(acc.x - lse, acc.y - lse, acc.z - lse, acc.w - lse);
    ((float4*)(out + (size_t)node * F_OUT))[l] = o;
}

extern "C" void kernel_launch(void* const* d_in, const int* in_sizes, int n_in,
                              void* d_out, int out_size, void* d_ws, size_t ws_size,
                              hipStream_t stream) {
    const float* x  = (const float*)d_in[0];
    const int*   ei = (const int*)d_in[1];
    const float* W1 = (const float*)d_in[2];
    const float* b1 = (const float*)d_in[3];
    const float* W2 = (const float*)d_in[4];
    const float* b2 = (const float*)d_in[5];
    float* out = (float*)d_out;

    // workspace layout (4B units)
    float* ws = (float*)d_ws;
    float* dinv          = ws;                          // [0, 100096)
    int*   offs          = (int*)(ws + 100096);         // 100001 used, reserve 100128
    int*   bucket_cnt    = (int*)(ws + 200224);         // 512
    int*   bucket_base   = (int*)(ws + 200736);         // 512 (NBUCK+1 used)
    int*   bucket_cursor = (int*)(ws + 201248);         // 512
    int*   csr           = (int*)(ws + 201760);         // 1,600,000
    float* h0            = ws + 1801760;                // 12.8M
    float* agg           = ws + 14601760;               // 12.8M
    int2*  binned        = (int2*)agg;                  // alias: dead before gather128 writes agg
    float* h2            = h0;                          // alias: h0 dead after gather128

    hipMemsetAsync(bucket_cnt, 0, 512 * sizeof(int), stream);
    hist_kernel<<<BIN_BLOCKS, 256, 0, stream>>>(ei, bucket_cnt);
    scan_kernel<<<1, 512, 0, stream>>>(bucket_cnt, bucket_base, bucket_cursor, offs);
    bin_kernel<<<BIN_BLOCKS, 256, 0, stream>>>(ei, bucket_cursor, binned);
    build_kernel<<<NBUCK, 256, 0, stream>>>(binned, bucket_base, offs, csr, dinv);
    gemm1_kernel<<<(N_NODES + 63) / 64, 256, 0, stream>>>(x, W1, h0);
    gather128<<<N_NODES / 8, 256, 0, stream>>>(h0, offs, csr, dinv, agg);
    gemm2_kernel<<<(N_NODES + 63) / 64, 256, 0, stream>>>(agg, b1, W2, h2);
    gather32_lsm<<<N_NODES / 32, 256, 0, stream>>>(h2, offs, csr, dinv, b2, out);
}

// Round 4
// 447.085 us; speedup vs baseline: 8.2231x; 1.0854x over previous
//
#include <hip/hip_runtime.h>

#define N_NODES 100000
#define N_EDGES 1600000
#define F_IN 256
#define F_HID 128
#define F_OUT 32
#define NBUCK 391           // ceil(100000/256) buckets of 256 node ids
#define BIN_BLOCKS 512
#define EDGES_PER_BIN 3125  // 512*3125 = 1,600,000

typedef unsigned short ushort_t;
typedef unsigned int uint_t;

__device__ __forceinline__ ushort_t f2bf(float f) {
    uint_t u = __float_as_uint(f);
    u += 0x7fff + ((u >> 16) & 1);  // RNE
    return (ushort_t)(u >> 16);
}
__device__ __forceinline__ float bf_lo(uint_t u) { return __uint_as_float(u << 16); }
__device__ __forceinline__ float bf_hi(uint_t u) { return __uint_as_float(u & 0xffff0000u); }

// ---------------- CSR build, pass 1: coarse histogram ----------------
__global__ __launch_bounds__(256) void hist_kernel(const int* __restrict__ ei,
                                                   int* __restrict__ bucket_cnt) {
    __shared__ int h[NBUCK];
    for (int i = threadIdx.x; i < NBUCK; i += 256) h[i] = 0;
    __syncthreads();
    int gid = blockIdx.x * 256 + threadIdx.x;
    for (int e = gid; e < N_EDGES; e += BIN_BLOCKS * 256)
        atomicAdd(&h[ei[N_EDGES + e] >> 8], 1);
    __syncthreads();
    for (int i = threadIdx.x; i < NBUCK; i += 256) {
        int c = h[i];
        if (c) atomicAdd(&bucket_cnt[i], c);
    }
}

// ---------------- CSR build: scan bucket counts ----------------
__global__ __launch_bounds__(512) void scan_kernel(const int* __restrict__ bucket_cnt,
                                                   int* __restrict__ bucket_base,
                                                   int* __restrict__ bucket_cursor,
                                                   int* __restrict__ offs) {
    __shared__ int s[512];
    int t = threadIdx.x;
    int own = (t < NBUCK) ? bucket_cnt[t] : 0;
    s[t] = own;
    __syncthreads();
    for (int off = 1; off < 512; off <<= 1) {
        int v = (t >= off) ? s[t - off] : 0;
        __syncthreads();
        s[t] += v;
        __syncthreads();
    }
    if (t < NBUCK) {
        int ex = s[t] - own;
        bucket_base[t] = ex;
        bucket_cursor[t] = ex;
    }
    if (t == 0) {
        bucket_base[NBUCK] = N_EDGES;
        offs[N_NODES] = N_EDGES;
    }
}

// ---------------- CSR build, pass 2: bin edges into bucket regions ----------------
__global__ __launch_bounds__(256) void bin_kernel(const int* __restrict__ ei,
                                                  int* __restrict__ bucket_cursor,
                                                  int2* __restrict__ binned) {
    __shared__ int h[NBUCK];
    __shared__ int base[NBUCK];
    const int t = threadIdx.x;
    const int beg = blockIdx.x * EDGES_PER_BIN;
    const int end = beg + EDGES_PER_BIN;
    for (int i = t; i < NBUCK; i += 256) h[i] = 0;
    __syncthreads();
    for (int e = beg + t; e < end; e += 256) atomicAdd(&h[ei[N_EDGES + e] >> 8], 1);
    __syncthreads();
    for (int i = t; i < NBUCK; i += 256) {
        int c = h[i];
        base[i] = c ? atomicAdd(&bucket_cursor[i], c) : 0;
        h[i] = 0;
    }
    __syncthreads();
    for (int e = beg + t; e < end; e += 256) {
        int s = ei[e], d = ei[N_EDGES + e];
        int bk = d >> 8;
        int p = base[bk] + atomicAdd(&h[bk], 1);
        binned[p] = make_int2(s, d);
    }
}

// ---------------- CSR build, pass 3: per-bucket offs/dinv/csr ----------------
__global__ __launch_bounds__(256) void build_kernel(const int2* __restrict__ binned,
                                                    const int* __restrict__ bucket_base,
                                                    int* __restrict__ offs,
                                                    int* __restrict__ csr,
                                                    float* __restrict__ dinv) {
    __shared__ int h[256];
    __shared__ int sc[256];
    __shared__ int cur[256];
    const int b = blockIdx.x, t = threadIdx.x;
    const int beg = bucket_base[b];
    const int end = bucket_base[b + 1];
    h[t] = 0;
    __syncthreads();
    for (int j = beg + t; j < end; j += 256) {
        int2 p = binned[j];
        atomicAdd(&h[p.y & 255], 1);
    }
    __syncthreads();
    int deg = h[t];
    sc[t] = deg;
    __syncthreads();
    for (int off = 1; off < 256; off <<= 1) {
        int v = (t >= off) ? sc[t - off] : 0;
        __syncthreads();
        sc[t] += v;
        __syncthreads();
    }
    int excl = sc[t] - deg;
    cur[t] = excl;
    int node = b * 256 + t;
    if (node < N_NODES) {
        offs[node] = beg + excl;
        dinv[node] = rsqrtf((float)deg + 1.0f);  // +1 self-loop
    }
    __syncthreads();
    for (int j = beg + t; j < end; j += 256) {
        int2 p = binned[j];
        int pos = atomicAdd(&cur[p.y & 255], 1);
        csr[beg + pos] = p.x;
    }
}

// ---------------- GEMM1: h0 = bf16(x @ W1)   [100000,256]x[256,128] ----------------
__global__ __launch_bounds__(256) void gemm1_kernel(const float* __restrict__ x,
                                                    const float* __restrict__ W1,
                                                    ushort_t* __restrict__ h0bf) {
    __shared__ float As[64][32];
    __shared__ float Bs[32][128];
    const int tid = threadIdx.x;
    const int rbase = blockIdx.x * 64;
    const int tm = tid >> 5;
    const int tn = tid & 31;

    float acc[8][4];
#pragma unroll
    for (int i = 0; i < 8; i++)
#pragma unroll
        for (int j = 0; j < 4; j++) acc[i][j] = 0.f;

    for (int k0 = 0; k0 < F_IN; k0 += 32) {
#pragma unroll
        for (int j = 0; j < 2; j++) {
            int f = tid * 2 + j;
            int row = f >> 3, c4 = f & 7;
            float4 v = make_float4(0.f, 0.f, 0.f, 0.f);
            int gr = rbase + row;
            if (gr < N_NODES) v = *(const float4*)(x + (size_t)gr * F_IN + k0 + c4 * 4);
            *(float4*)(&As[row][c4 * 4]) = v;
        }
#pragma unroll
        for (int j = 0; j < 4; j++) {
            int f = tid + 256 * j;
            int row = f >> 5, c4 = f & 31;
            *(float4*)(&Bs[row][c4 * 4]) = *(const float4*)(W1 + (size_t)(k0 + row) * F_HID + c4 * 4);
        }
        __syncthreads();
#pragma unroll
        for (int k = 0; k < 32; k++) {
            float4 b4 = *(const float4*)(&Bs[k][tn * 4]);
#pragma unroll
            for (int i = 0; i < 8; i++) {
                float a = As[tm * 8 + i][k];
                acc[i][0] += a * b4.x;
                acc[i][1] += a * b4.y;
                acc[i][2] += a * b4.z;
                acc[i][3] += a * b4.w;
            }
        }
        __syncthreads();
    }
#pragma unroll
    for (int i = 0; i < 8; i++) {
        int r = rbase + tm * 8 + i;
        if (r < N_NODES) {
            uint2 p;
            p.x = (uint_t)f2bf(acc[i][0]) | ((uint_t)f2bf(acc[i][1]) << 16);
            p.y = (uint_t)f2bf(acc[i][2]) | ((uint_t)f2bf(acc[i][3]) << 16);
            *(uint2*)(h0bf + (size_t)r * F_HID + tn * 4) = p;
        }
    }
}

// ---------------- gather aggregation layer 1 (bf16 rows, fp32 acc) ----------------
__global__ __launch_bounds__(256) void gather128(const ushort_t* __restrict__ h0bf,
                                                 const int* __restrict__ offs,
                                                 const int* __restrict__ csr,
                                                 const float* __restrict__ dinv,
                                                 ushort_t* __restrict__ aggbf) {
    int node = blockIdx.x * 8 + (threadIdx.x >> 5);
    int l = threadIdx.x & 31;
    float dn = dinv[node];
    uint2 sv = ((const uint2*)(h0bf + (size_t)node * F_HID))[l];
    float s = dn * dn;
    float4 acc;
    acc.x = bf_lo(sv.x) * s; acc.y = bf_hi(sv.x) * s;
    acc.z = bf_lo(sv.y) * s; acc.w = bf_hi(sv.y) * s;

    int beg = offs[node], end = offs[node + 1];
    int j = beg;
    for (; j + 1 < end; j += 2) {
        int s0 = csr[j], s1 = csr[j + 1];
        float n0 = dinv[s0] * dn, n1 = dinv[s1] * dn;
        uint2 v0 = ((const uint2*)(h0bf + (size_t)s0 * F_HID))[l];
        uint2 v1 = ((const uint2*)(h0bf + (size_t)s1 * F_HID))[l];
        acc.x += bf_lo(v0.x) * n0 + bf_lo(v1.x) * n1;
        acc.y += bf_hi(v0.x) * n0 + bf_hi(v1.x) * n1;
        acc.z += bf_lo(v0.y) * n0 + bf_lo(v1.y) * n1;
        acc.w += bf_hi(v0.y) * n0 + bf_hi(v1.y) * n1;
    }
    if (j < end) {
        int s0 = csr[j];
        float n0 = dinv[s0] * dn;
        uint2 v0 = ((const uint2*)(h0bf + (size_t)s0 * F_HID))[l];
        acc.x += bf_lo(v0.x) * n0; acc.y += bf_hi(v0.x) * n0;
        acc.z += bf_lo(v0.y) * n0; acc.w += bf_hi(v0.y) * n0;
    }
    uint2 p;
    p.x = (uint_t)f2bf(acc.x) | ((uint_t)f2bf(acc.y) << 16);
    p.y = (uint_t)f2bf(acc.z) | ((uint_t)f2bf(acc.w) << 16);
    ((uint2*)(aggbf + (size_t)node * F_HID))[l] = p;
}

// ---------------- GEMM2: h2 = bf16(relu(agg + b1) @ W2) ----------------
__global__ __launch_bounds__(256) void gemm2_kernel(const ushort_t* __restrict__ aggbf,
                                                    const float* __restrict__ b1,
                                                    const float* __restrict__ W2,
                                                    ushort_t* __restrict__ h2bf) {
    __shared__ float Ws[F_HID * F_OUT];
    __shared__ float As[64][F_HID + 1];
    __shared__ float b1s[F_HID];
    const int tid = threadIdx.x;
    const int rbase = blockIdx.x * 64;

    if (tid < F_HID) b1s[tid] = b1[tid];
#pragma unroll
    for (int j = 0; j < 4; j++) {
        int f = tid + 256 * j;
        ((float4*)Ws)[f] = ((const float4*)W2)[f];
    }
    __syncthreads();

    // A tile: 64 rows x 128 bf16 = 64x16 uint4 (8 bf16 each); 1024 loads, 4/thread
#pragma unroll
    for (int j = 0; j < 4; j++) {
        int f = tid + 256 * j;
        int row = f >> 4, u4 = f & 15;
        int gr = rbase + row;
        uint4 v = make_uint4(0, 0, 0, 0);
        if (gr < N_NODES) v = ((const uint4*)(aggbf + (size_t)gr * F_HID))[u4];
        int c = u4 * 8;
        As[row][c + 0] = fmaxf(bf_lo(v.x) + b1s[c + 0], 0.f);
        As[row][c + 1] = fmaxf(bf_hi(v.x) + b1s[c + 1], 0.f);
        As[row][c + 2] = fmaxf(bf_lo(v.y) + b1s[c + 2], 0.f);
        As[row][c + 3] = fmaxf(bf_hi(v.y) + b1s[c + 3], 0.f);
        As[row][c + 4] = fmaxf(bf_lo(v.z) + b1s[c + 4], 0.f);
        As[row][c + 5] = fmaxf(bf_hi(v.z) + b1s[c + 5], 0.f);
        As[row][c + 6] = fmaxf(bf_lo(v.w) + b1s[c + 6], 0.f);
        As[row][c + 7] = fmaxf(bf_hi(v.w) + b1s[c + 7], 0.f);
    }
    __syncthreads();

    const int r = tid >> 2;
    const int c0 = (tid & 3) * 8;
    float acc[8] = {0, 0, 0, 0, 0, 0, 0, 0};
#pragma unroll 4
    for (int k = 0; k < F_HID; k++) {
        float a = As[r][k];
#pragma unroll
        for (int j = 0; j < 8; j++) acc[j] += a * Ws[k * F_OUT + c0 + j];
    }
    int gr = rbase + r;
    if (gr < N_NODES) {
        uint4 p;
        p.x = (uint_t)f2bf(acc[0]) | ((uint_t)f2bf(acc[1]) << 16);
        p.y = (uint_t)f2bf(acc[2]) | ((uint_t)f2bf(acc[3]) << 16);
        p.z = (uint_t)f2bf(acc[4]) | ((uint_t)f2bf(acc[5]) << 16);
        p.w = (uint_t)f2bf(acc[6]) | ((uint_t)f2bf(acc[7]) << 16);
        *(uint4*)(h2bf + (size_t)gr * F_OUT + c0) = p;
    }
}

// ---------------- gather aggregation layer 2 + bias + log_softmax ----------------
__global__ __launch_bounds__(256) void gather32_lsm(const ushort_t* __restrict__ h2bf,
                                                    const int* __restrict__ offs,
                                                    const int* __restrict__ csr,
                                                    const float* __restrict__ dinv,
                                                    const float* __restrict__ b2,
                                                    float* __restrict__ out) {
    int node = blockIdx.x * 32 + (threadIdx.x >> 3);
    int l = threadIdx.x & 7;
    float dn = dinv[node];
    uint2 sv = ((const uint2*)(h2bf + (size_t)node * F_OUT))[l];
    float s = dn * dn;
    float4 acc;
    acc.x = bf_lo(sv.x) * s; acc.y = bf_hi(sv.x) * s;
    acc.z = bf_lo(sv.y) * s; acc.w = bf_hi(sv.y) * s;

    int beg = offs[node], end = offs[node + 1];
    int j = beg;
    for (; j + 1 < end; j += 2) {
        int s0 = csr[j], s1 = csr[j + 1];
        float n0 = dinv[s0] * dn, n1 = dinv[s1] * dn;
        uint2 v0 = ((const uint2*)(h2bf + (size_t)s0 * F_OUT))[l];
        uint2 v1 = ((const uint2*)(h2bf + (size_t)s1 * F_OUT))[l];
        acc.x += bf_lo(v0.x) * n0 + bf_lo(v1.x) * n1;
        acc.y += bf_hi(v0.x) * n0 + bf_hi(v1.x) * n1;
        acc.z += bf_lo(v0.y) * n0 + bf_lo(v1.y) * n1;
        acc.w += bf_hi(v0.y) * n0 + bf_hi(v1.y) * n1;
    }
    if (j < end) {
        int s0 = csr[j];
        float n0 = dinv[s0] * dn;
        uint2 v0 = ((const uint2*)(h2bf + (size_t)s0 * F_OUT))[l];
        acc.x += bf_lo(v0.x) * n0; acc.y += bf_hi(v0.x) * n0;
        acc.z += bf_lo(v0.y) * n0; acc.w += bf_hi(v0.y) * n0;
    }
    float4 bb = ((const float4*)b2)[l];
    acc.x += bb.x; acc.y += bb.y; acc.z += bb.z; acc.w += bb.w;

    float m = fmaxf(fmaxf(acc.x, acc.y), fmaxf(acc.z, acc.w));
#pragma unroll
    for (int off = 1; off < 8; off <<= 1) m = fmaxf(m, __shfl_xor(m, off, 8));
    float es = __expf(acc.x - m) + __expf(acc.y - m) + __expf(acc.z - m) + __expf(acc.w - m);
#pragma unroll
    for (int off = 1; off < 8; off <<= 1) es += __shfl_xor(es, off, 8);
    float lse = m + __logf(es);
    float4 o = make_float4(acc.x - lse, acc.y - lse, acc.z - lse, acc.w - lse);
    ((float4*)(out + (size_t)node * F_OUT))[l] = o;
}

extern "C" void kernel_launch(void* const* d_in, const int* in_sizes, int n_in,
                              void* d_out, int out_size, void* d_ws, size_t ws_size,
                              hipStream_t stream) {
    const float* x  = (const float*)d_in[0];
    const int*   ei = (const int*)d_in[1];
    const float* W1 = (const float*)d_in[2];
    const float* b1 = (const float*)d_in[3];
    const float* W2 = (const float*)d_in[4];
    const float* b2 = (const float*)d_in[5];
    float* out = (float*)d_out;

    // workspace layout (4B units)
    float* ws = (float*)d_ws;
    float*    dinv          = ws;                      // 100096
    int*      offs          = (int*)(ws + 100096);     // 100128
    int*      bucket_cnt    = (int*)(ws + 200224);     // 512
    int*      bucket_base   = (int*)(ws + 200736);     // 512
    int*      bucket_cursor = (int*)(ws + 201248);     // 512
    int*      csr           = (int*)(ws + 201760);     // 1,600,000
    ushort_t* h0bf          = (ushort_t*)(ws + 1801760);  // 12.8M ushort = 6.4M floats
    ushort_t* aggbf         = (ushort_t*)(ws + 8201760);  // 12.8M ushort = 6.4M floats
    ushort_t* h2bf          = (ushort_t*)(ws + 14601760); // 3.2M ushort = 1.6M floats
    int2*     binned        = (int2*)aggbf;               // alias: dead before gather128 writes agg

    hipMemsetAsync(bucket_cnt, 0, 512 * sizeof(int), stream);
    hist_kernel<<<BIN_BLOCKS, 256, 0, stream>>>(ei, bucket_cnt);
    scan_kernel<<<1, 512, 0, stream>>>(bucket_cnt, bucket_base, bucket_cursor, offs);
    bin_kernel<<<BIN_BLOCKS, 256, 0, stream>>>(ei, bucket_cursor, binned);
    build_kernel<<<NBUCK, 256, 0, stream>>>(binned, bucket_base, offs, csr, dinv);
    gemm1_kernel<<<(N_NODES + 63) / 64, 256, 0, stream>>>(x, W1, h0bf);
    gather128<<<N_NODES / 8, 256, 0, stream>>>(h0bf, offs, csr, dinv, aggbf);
    gemm2_kernel<<<(N_NODES + 63) / 64, 256, 0, stream>>>(aggbf, b1, W2, h2bf);
    gather32_lsm<<<N_NODES / 32, 256, 0, stream>>>(h2bf, offs, csr, dinv, b2, out);
}

// Round 5
// 400.497 us; speedup vs baseline: 9.1796x; 1.1163x over previous
//
#include <hip/hip_runtime.h>

#define N_NODES 100000
#define N_EDGES 1600000
#define F_IN 256
#define F_HID 128
#define F_OUT 32
#define NBUCK 391           // ceil(100000/256) buckets of 256 node ids
#define BIN_BLOCKS 512
#define EDGES_PER_BIN 3125  // 512*3125 = 1,600,000

typedef unsigned short ushort_t;
typedef unsigned int uint_t;

using short8  = __attribute__((ext_vector_type(8))) short;
using floatx4 = __attribute__((ext_vector_type(4))) float;

__device__ __forceinline__ ushort_t f2bf(float f) {
    uint_t u = __float_as_uint(f);
    u += 0x7fff + ((u >> 16) & 1);  // RNE
    return (ushort_t)(u >> 16);
}
__device__ __forceinline__ float bf_lo(uint_t u) { return __uint_as_float(u << 16); }
__device__ __forceinline__ float bf_hi(uint_t u) { return __uint_as_float(u & 0xffff0000u); }

// ---------------- CSR build, pass 1: coarse histogram ----------------
__global__ __launch_bounds__(256) void hist_kernel(const int* __restrict__ ei,
                                                   int* __restrict__ bucket_cnt) {
    __shared__ int h[NBUCK];
    for (int i = threadIdx.x; i < NBUCK; i += 256) h[i] = 0;
    __syncthreads();
    int gid = blockIdx.x * 256 + threadIdx.x;
    for (int e = gid; e < N_EDGES; e += BIN_BLOCKS * 256)
        atomicAdd(&h[ei[N_EDGES + e] >> 8], 1);
    __syncthreads();
    for (int i = threadIdx.x; i < NBUCK; i += 256) {
        int c = h[i];
        if (c) atomicAdd(&bucket_cnt[i], c);
    }
}

// ---------------- CSR build: scan bucket counts ----------------
__global__ __launch_bounds__(512) void scan_kernel(const int* __restrict__ bucket_cnt,
                                                   int* __restrict__ bucket_base,
                                                   int* __restrict__ bucket_cursor,
                                                   int* __restrict__ offs) {
    __shared__ int s[512];
    int t = threadIdx.x;
    int own = (t < NBUCK) ? bucket_cnt[t] : 0;
    s[t] = own;
    __syncthreads();
    for (int off = 1; off < 512; off <<= 1) {
        int v = (t >= off) ? s[t - off] : 0;
        __syncthreads();
        s[t] += v;
        __syncthreads();
    }
    if (t < NBUCK) {
        int ex = s[t] - own;
        bucket_base[t] = ex;
        bucket_cursor[t] = ex;
    }
    if (t == 0) {
        bucket_base[NBUCK] = N_EDGES;
        offs[N_NODES] = N_EDGES;
    }
}

// ---------------- CSR build, pass 2: bin edges into bucket regions ----------------
__global__ __launch_bounds__(256) void bin_kernel(const int* __restrict__ ei,
                                                  int* __restrict__ bucket_cursor,
                                                  int2* __restrict__ binned) {
    __shared__ int h[NBUCK];
    __shared__ int base[NBUCK];
    const int t = threadIdx.x;
    const int beg = blockIdx.x * EDGES_PER_BIN;
    const int end = beg + EDGES_PER_BIN;
    for (int i = t; i < NBUCK; i += 256) h[i] = 0;
    __syncthreads();
    for (int e = beg + t; e < end; e += 256) atomicAdd(&h[ei[N_EDGES + e] >> 8], 1);
    __syncthreads();
    for (int i = t; i < NBUCK; i += 256) {
        int c = h[i];
        base[i] = c ? atomicAdd(&bucket_cursor[i], c) : 0;
        h[i] = 0;
    }
    __syncthreads();
    for (int e = beg + t; e < end; e += 256) {
        int s = ei[e], d = ei[N_EDGES + e];
        int bk = d >> 8;
        int p = base[bk] + atomicAdd(&h[bk], 1);
        binned[p] = make_int2(s, d);
    }
}

// ---------------- CSR build, pass 3: per-bucket offs/dinv/csr ----------------
__global__ __launch_bounds__(256) void build_kernel(const int2* __restrict__ binned,
                                                    const int* __restrict__ bucket_base,
                                                    int* __restrict__ offs,
                                                    int* __restrict__ csr,
                                                    float* __restrict__ dinv) {
    __shared__ int h[256];
    __shared__ int sc[256];
    __shared__ int cur[256];
    const int b = blockIdx.x, t = threadIdx.x;
    const int beg = bucket_base[b];
    const int end = bucket_base[b + 1];
    h[t] = 0;
    __syncthreads();
    for (int j = beg + t; j < end; j += 256) {
        int2 p = binned[j];
        atomicAdd(&h[p.y & 255], 1);
    }
    __syncthreads();
    int deg = h[t];
    sc[t] = deg;
    __syncthreads();
    for (int off = 1; off < 256; off <<= 1) {
        int v = (t >= off) ? sc[t - off] : 0;
        __syncthreads();
        sc[t] += v;
        __syncthreads();
    }
    int excl = sc[t] - deg;
    cur[t] = excl;
    int node = b * 256 + t;
    if (node < N_NODES) {
        offs[node] = beg + excl;
        dinv[node] = rsqrtf((float)deg + 1.0f);  // +1 self-loop
    }
    __syncthreads();
    for (int j = beg + t; j < end; j += 256) {
        int2 p = binned[j];
        int pos = atomicAdd(&cur[p.y & 255], 1);
        csr[beg + pos] = p.x;
    }
}

// ---------------- W1 transpose -> bf16  [256][128] -> [128][256] ----------------
__global__ __launch_bounds__(256) void w1t_kernel(const float* __restrict__ W1,
                                                  ushort_t* __restrict__ W1T) {
    int t = blockIdx.x * 256 + threadIdx.x;  // 8192 threads
#pragma unroll
    for (int j = 0; j < 4; j++) {
        int e = j * 8192 + t;                // e = n*256 + k  (coalesced writes)
        int n = e >> 8, k = e & 255;
        W1T[e] = f2bf(W1[k * F_HID + n]);
    }
}

// ---------------- GEMM1 (MFMA): h0 = bf16(x @ W1)  [100000,256]x[256,128] ----------------
// Block: 64 rows x 128 cols, 4 waves (each wave 16 rows x full 128 cols).
// W1T staged in LDS as [n][k] bf16 with +8 pad; A-frags read from global fp32 x.
__global__ __launch_bounds__(256) void gemm1_kernel(const float* __restrict__ x,
                                                    const ushort_t* __restrict__ W1T,
                                                    ushort_t* __restrict__ h0bf) {
    __shared__ ushort_t Bst[F_HID][F_IN + 8];  // 128 x 264 bf16 = 66 KB
    const int tid = threadIdx.x;
    const int rbase = blockIdx.x * 64;
    const int w = tid >> 6;        // wave 0..3
    const int lane = tid & 63;
    const int q = lane >> 4;       // quad 0..3
    const int nloc = lane & 15;    // 0..15

    // stage W1T -> LDS (4096 x 16B, coalesced)
#pragma unroll
    for (int j = 0; j < 16; j++) {
        int f = j * 256 + tid;           // 0..4095
        int n = f >> 5, kg = f & 31;     // kg: 8-bf16 group
        uint4 v = ((const uint4*)(W1T + n * F_IN))[kg];
        *(uint4*)(&Bst[n][kg * 8]) = v;
    }
    __syncthreads();

    const int rowA = rbase + w * 16 + nloc;
    const bool okA = rowA < N_NODES;
    const float* ap = x + (size_t)rowA * F_IN + q * 8;

    floatx4 acc[8];
#pragma unroll
    for (int t = 0; t < 8; t++) acc[t] = (floatx4){0.f, 0.f, 0.f, 0.f};

#pragma unroll
    for (int k0 = 0; k0 < F_IN; k0 += 32) {
        float4 f0 = make_float4(0.f, 0.f, 0.f, 0.f);
        float4 f1 = make_float4(0.f, 0.f, 0.f, 0.f);
        if (okA) {
            f0 = *(const float4*)(ap + k0);
            f1 = *(const float4*)(ap + k0 + 4);
        }
        short8 a;
        a[0] = (short)f2bf(f0.x); a[1] = (short)f2bf(f0.y);
        a[2] = (short)f2bf(f0.z); a[3] = (short)f2bf(f0.w);
        a[4] = (short)f2bf(f1.x); a[5] = (short)f2bf(f1.y);
        a[6] = (short)f2bf(f1.z); a[7] = (short)f2bf(f1.w);
#pragma unroll
        for (int t = 0; t < 8; t++) {
            short8 b = *(const short8*)(&Bst[t * 16 + nloc][k0 + q * 8]);
            acc[t] = __builtin_amdgcn_mfma_f32_16x16x32_bf16(a, b, acc[t], 0, 0, 0);
        }
    }

    // D layout: col = lane&15 (n within tile), row = q*4 + reg
#pragma unroll
    for (int reg = 0; reg < 4; reg++) {
        int rowD = rbase + w * 16 + q * 4 + reg;
        if (rowD < N_NODES) {
            ushort_t* op = h0bf + (size_t)rowD * F_HID + nloc;
#pragma unroll
            for (int t = 0; t < 8; t++) op[t * 16] = f2bf(acc[t][reg]);
        }
    }
}

// ---------------- gather aggregation layer 1 (bf16 rows, fp32 acc) ----------------
__global__ __launch_bounds__(256) void gather128(const ushort_t* __restrict__ h0bf,
                                                 const int* __restrict__ offs,
                                                 const int* __restrict__ csr,
                                                 const float* __restrict__ dinv,
                                                 ushort_t* __restrict__ aggbf) {
    int node = blockIdx.x * 8 + (threadIdx.x >> 5);
    int l = threadIdx.x & 31;
    float dn = dinv[node];
    uint2 sv = ((const uint2*)(h0bf + (size_t)node * F_HID))[l];
    float s = dn * dn;
    float4 acc;
    acc.x = bf_lo(sv.x) * s; acc.y = bf_hi(sv.x) * s;
    acc.z = bf_lo(sv.y) * s; acc.w = bf_hi(sv.y) * s;

    int beg = offs[node], end = offs[node + 1];
    int j = beg;
    for (; j + 1 < end; j += 2) {
        int s0 = csr[j], s1 = csr[j + 1];
        float n0 = dinv[s0] * dn, n1 = dinv[s1] * dn;
        uint2 v0 = ((const uint2*)(h0bf + (size_t)s0 * F_HID))[l];
        uint2 v1 = ((const uint2*)(h0bf + (size_t)s1 * F_HID))[l];
        acc.x += bf_lo(v0.x) * n0 + bf_lo(v1.x) * n1;
        acc.y += bf_hi(v0.x) * n0 + bf_hi(v1.x) * n1;
        acc.z += bf_lo(v0.y) * n0 + bf_lo(v1.y) * n1;
        acc.w += bf_hi(v0.y) * n0 + bf_hi(v1.y) * n1;
    }
    if (j < end) {
        int s0 = csr[j];
        float n0 = dinv[s0] * dn;
        uint2 v0 = ((const uint2*)(h0bf + (size_t)s0 * F_HID))[l];
        acc.x += bf_lo(v0.x) * n0; acc.y += bf_hi(v0.x) * n0;
        acc.z += bf_lo(v0.y) * n0; acc.w += bf_hi(v0.y) * n0;
    }
    uint2 p;
    p.x = (uint_t)f2bf(acc.x) | ((uint_t)f2bf(acc.y) << 16);
    p.y = (uint_t)f2bf(acc.z) | ((uint_t)f2bf(acc.w) << 16);
    ((uint2*)(aggbf + (size_t)node * F_HID))[l] = p;
}

// ---------------- GEMM2: h2 = bf16(relu(agg + b1) @ W2) ----------------
__global__ __launch_bounds__(256) void gemm2_kernel(const ushort_t* __restrict__ aggbf,
                                                    const float* __restrict__ b1,
                                                    const float* __restrict__ W2,
                                                    ushort_t* __restrict__ h2bf) {
    __shared__ float Ws[F_HID * F_OUT];
    __shared__ float As[64][F_HID + 1];
    __shared__ float b1s[F_HID];
    const int tid = threadIdx.x;
    const int rbase = blockIdx.x * 64;

    if (tid < F_HID) b1s[tid] = b1[tid];
#pragma unroll
    for (int j = 0; j < 4; j++) {
        int f = tid + 256 * j;
        ((float4*)Ws)[f] = ((const float4*)W2)[f];
    }
    __syncthreads();

#pragma unroll
    for (int j = 0; j < 4; j++) {
        int f = tid + 256 * j;
        int row = f >> 4, u4 = f & 15;
        int gr = rbase + row;
        uint4 v = make_uint4(0, 0, 0, 0);
        if (gr < N_NODES) v = ((const uint4*)(aggbf + (size_t)gr * F_HID))[u4];
        int c = u4 * 8;
        As[row][c + 0] = fmaxf(bf_lo(v.x) + b1s[c + 0], 0.f);
        As[row][c + 1] = fmaxf(bf_hi(v.x) + b1s[c + 1], 0.f);
        As[row][c + 2] = fmaxf(bf_lo(v.y) + b1s[c + 2], 0.f);
        As[row][c + 3] = fmaxf(bf_hi(v.y) + b1s[c + 3], 0.f);
        As[row][c + 4] = fmaxf(bf_lo(v.z) + b1s[c + 4], 0.f);
        As[row][c + 5] = fmaxf(bf_hi(v.z) + b1s[c + 5], 0.f);
        As[row][c + 6] = fmaxf(bf_lo(v.w) + b1s[c + 6], 0.f);
        As[row][c + 7] = fmaxf(bf_hi(v.w) + b1s[c + 7], 0.f);
    }
    __syncthreads();

    const int r = tid >> 2;
    const int c0 = (tid & 3) * 8;
    float acc[8] = {0, 0, 0, 0, 0, 0, 0, 0};
#pragma unroll 4
    for (int k = 0; k < F_HID; k++) {
        float a = As[r][k];
#pragma unroll
        for (int j = 0; j < 8; j++) acc[j] += a * Ws[k * F_OUT + c0 + j];
    }
    int gr = rbase + r;
    if (gr < N_NODES) {
        uint4 p;
        p.x = (uint_t)f2bf(acc[0]) | ((uint_t)f2bf(acc[1]) << 16);
        p.y = (uint_t)f2bf(acc[2]) | ((uint_t)f2bf(acc[3]) << 16);
        p.z = (uint_t)f2bf(acc[4]) | ((uint_t)f2bf(acc[5]) << 16);
        p.w = (uint_t)f2bf(acc[6]) | ((uint_t)f2bf(acc[7]) << 16);
        *(uint4*)(h2bf + (size_t)gr * F_OUT + c0) = p;
    }
}

// ---------------- gather aggregation layer 2 + bias + log_softmax ----------------
__global__ __launch_bounds__(256) void gather32_lsm(const ushort_t* __restrict__ h2bf,
                                                    const int* __restrict__ offs,
                                                    const int* __restrict__ csr,
                                                    const float* __restrict__ dinv,
                                                    const float* __restrict__ b2,
                                                    float* __restrict__ out) {
    int node = blockIdx.x * 32 + (threadIdx.x >> 3);
    int l = threadIdx.x & 7;
    float dn = dinv[node];
    uint2 sv = ((const uint2*)(h2bf + (size_t)node * F_OUT))[l];
    float s = dn * dn;
    float4 acc;
    acc.x = bf_lo(sv.x) * s; acc.y = bf_hi(sv.x) * s;
    acc.z = bf_lo(sv.y) * s; acc.w = bf_hi(sv.y) * s;

    int beg = offs[node], end = offs[node + 1];
    int j = beg;
    for (; j + 1 < end; j += 2) {
        int s0 = csr[j], s1 = csr[j + 1];
        float n0 = dinv[s0] * dn, n1 = dinv[s1] * dn;
        uint2 v0 = ((const uint2*)(h2bf + (size_t)s0 * F_OUT))[l];
        uint2 v1 = ((const uint2*)(h2bf + (size_t)s1 * F_OUT))[l];
        acc.x += bf_lo(v0.x) * n0 + bf_lo(v1.x) * n1;
        acc.y += bf_hi(v0.x) * n0 + bf_hi(v1.x) * n1;
        acc.z += bf_lo(v0.y) * n0 + bf_lo(v1.y) * n1;
        acc.w += bf_hi(v0.y) * n0 + bf_hi(v1.y) * n1;
    }
    if (j < end) {
        int s0 = csr[j];
        float n0 = dinv[s0] * dn;
        uint2 v0 = ((const uint2*)(h2bf + (size_t)s0 * F_OUT))[l];
        acc.x += bf_lo(v0.x) * n0; acc.y += bf_hi(v0.x) * n0;
        acc.z += bf_lo(v0.y) * n0; acc.w += bf_hi(v0.y) * n0;
    }
    float4 bb = ((const float4*)b2)[l];
    acc.x += bb.x; acc.y += bb.y; acc.z += bb.z; acc.w += bb.w;

    float m = fmaxf(fmaxf(acc.x, acc.y), fmaxf(acc.z, acc.w));
#pragma unroll
    for (int off = 1; off < 8; off <<= 1) m = fmaxf(m, __shfl_xor(m, off, 8));
    float es = __expf(acc.x - m) + __expf(acc.y - m) + __expf(acc.z - m) + __expf(acc.w - m);
#pragma unroll
    for (int off = 1; off < 8; off <<= 1) es += __shfl_xor(es, off, 8);
    float lse = m + __logf(es);
    float4 o = make_float4(acc.x - lse, acc.y - lse, acc.z - lse, acc.w - lse);
    ((float4*)(out + (size_t)node * F_OUT))[l] = o;
}

extern "C" void kernel_launch(void* const* d_in, const int* in_sizes, int n_in,
                              void* d_out, int out_size, void* d_ws, size_t ws_size,
                              hipStream_t stream) {
    const float* x  = (const float*)d_in[0];
    const int*   ei = (const int*)d_in[1];
    const float* W1 = (const float*)d_in[2];
    const float* b1 = (const float*)d_in[3];
    const float* W2 = (const float*)d_in[4];
    const float* b2 = (const float*)d_in[5];
    float* out = (float*)d_out;

    // workspace layout (4B units)
    float* ws = (float*)d_ws;
    float*    dinv          = ws;                      // 100096
    int*      offs          = (int*)(ws + 100096);     // 100128
    int*      bucket_cnt    = (int*)(ws + 200224);     // 512
    int*      bucket_base   = (int*)(ws + 200736);     // 512
    int*      bucket_cursor = (int*)(ws + 201248);     // 512
    int*      csr           = (int*)(ws + 201760);     // 1,600,000
    ushort_t* W1T           = (ushort_t*)(ws + 1801760);   // 32768 ushort = 16384 floats
    ushort_t* h0bf          = (ushort_t*)(ws + 1818144);   // 12.8M ushort = 6.4M floats
    ushort_t* aggbf         = (ushort_t*)(ws + 8218144);   // 12.8M ushort = 6.4M floats
    ushort_t* h2bf          = (ushort_t*)(ws + 14618144);  // 3.2M ushort = 1.6M floats
    int2*     binned        = (int2*)aggbf;                // alias: dead before gather128 writes agg

    hipMemsetAsync(bucket_cnt, 0, 512 * sizeof(int), stream);
    hist_kernel<<<BIN_BLOCKS, 256, 0, stream>>>(ei, bucket_cnt);
    scan_kernel<<<1, 512, 0, stream>>>(bucket_cnt, bucket_base, bucket_cursor, offs);
    bin_kernel<<<BIN_BLOCKS, 256, 0, stream>>>(ei, bucket_cursor, binned);
    build_kernel<<<NBUCK, 256, 0, stream>>>(binned, bucket_base, offs, csr, dinv);
    w1t_kernel<<<32, 256, 0, stream>>>(W1, W1T);
    gemm1_kernel<<<(N_NODES + 63) / 64, 256, 0, stream>>>(x, W1T, h0bf);
    gather128<<<N_NODES / 8, 256, 0, stream>>>(h0bf, offs, csr, dinv, aggbf);
    gemm2_kernel<<<(N_NODES + 63) / 64, 256, 0, stream>>>(aggbf, b1, W2, h2bf);
    gather32_lsm<<<N_NODES / 32, 256, 0, stream>>>(h2bf, offs, csr, dinv, b2, out);
}

// Round 6
// 361.023 us; speedup vs baseline: 10.1833x; 1.1093x over previous
//
#include <hip/hip_runtime.h>

#define N_NODES 100000
#define N_EDGES 1600000
#define F_IN 256
#define F_HID 128
#define F_OUT 32
#define NBUCK 391           // ceil(100000/256) buckets of 256 node ids
#define BIN_BLOCKS 512
#define EDGES_PER_BIN 3125  // 512*3125 = 1,600,000

typedef unsigned short ushort_t;
typedef unsigned int uint_t;

using short8  = __attribute__((ext_vector_type(8))) short;
using floatx4 = __attribute__((ext_vector_type(4))) float;

__device__ __forceinline__ ushort_t f2bf(float f) {
    uint_t u = __float_as_uint(f);
    u += 0x7fff + ((u >> 16) & 1);  // RNE
    return (ushort_t)(u >> 16);
}
__device__ __forceinline__ float bf_lo(uint_t u) { return __uint_as_float(u << 16); }
__device__ __forceinline__ float bf_hi(uint_t u) { return __uint_as_float(u & 0xffff0000u); }

// ---------------- CSR build, pass 1: coarse histogram ----------------
__global__ __launch_bounds__(256) void hist_kernel(const int* __restrict__ ei,
                                                   int* __restrict__ bucket_cnt) {
    __shared__ int h[NBUCK];
    for (int i = threadIdx.x; i < NBUCK; i += 256) h[i] = 0;
    __syncthreads();
    int gid = blockIdx.x * 256 + threadIdx.x;
    for (int e = gid; e < N_EDGES; e += BIN_BLOCKS * 256)
        atomicAdd(&h[ei[N_EDGES + e] >> 8], 1);
    __syncthreads();
    for (int i = threadIdx.x; i < NBUCK; i += 256) {
        int c = h[i];
        if (c) atomicAdd(&bucket_cnt[i], c);
    }
}

// ---------------- CSR build: scan bucket counts ----------------
__global__ __launch_bounds__(512) void scan_kernel(const int* __restrict__ bucket_cnt,
                                                   int* __restrict__ bucket_base,
                                                   int* __restrict__ bucket_cursor,
                                                   int* __restrict__ offs) {
    __shared__ int s[512];
    int t = threadIdx.x;
    int own = (t < NBUCK) ? bucket_cnt[t] : 0;
    s[t] = own;
    __syncthreads();
    for (int off = 1; off < 512; off <<= 1) {
        int v = (t >= off) ? s[t - off] : 0;
        __syncthreads();
        s[t] += v;
        __syncthreads();
    }
    if (t < NBUCK) {
        int ex = s[t] - own;
        bucket_base[t] = ex;
        bucket_cursor[t] = ex;
    }
    if (t == 0) {
        bucket_base[NBUCK] = N_EDGES;
        offs[N_NODES] = N_EDGES;
    }
}

// ---------------- CSR build, pass 2: bin edges into bucket regions ----------------
__global__ __launch_bounds__(256) void bin_kernel(const int* __restrict__ ei,
                                                  int* __restrict__ bucket_cursor,
                                                  int2* __restrict__ binned) {
    __shared__ int h[NBUCK];
    __shared__ int base[NBUCK];
    const int t = threadIdx.x;
    const int beg = blockIdx.x * EDGES_PER_BIN;
    const int end = beg + EDGES_PER_BIN;
    for (int i = t; i < NBUCK; i += 256) h[i] = 0;
    __syncthreads();
    for (int e = beg + t; e < end; e += 256) atomicAdd(&h[ei[N_EDGES + e] >> 8], 1);
    __syncthreads();
    for (int i = t; i < NBUCK; i += 256) {
        int c = h[i];
        base[i] = c ? atomicAdd(&bucket_cursor[i], c) : 0;
        h[i] = 0;
    }
    __syncthreads();
    for (int e = beg + t; e < end; e += 256) {
        int s = ei[e], d = ei[N_EDGES + e];
        int bk = d >> 8;
        int p = base[bk] + atomicAdd(&h[bk], 1);
        binned[p] = make_int2(s, d);
    }
}

// ---------------- CSR build, pass 3: per-bucket offs/dinv/csr ----------------
__global__ __launch_bounds__(256) void build_kernel(const int2* __restrict__ binned,
                                                    const int* __restrict__ bucket_base,
                                                    int* __restrict__ offs,
                                                    int* __restrict__ csr,
                                                    float* __restrict__ dinv) {
    __shared__ int h[256];
    __shared__ int sc[256];
    __shared__ int cur[256];
    const int b = blockIdx.x, t = threadIdx.x;
    const int beg = bucket_base[b];
    const int end = bucket_base[b + 1];
    h[t] = 0;
    __syncthreads();
    for (int j = beg + t; j < end; j += 256) {
        int2 p = binned[j];
        atomicAdd(&h[p.y & 255], 1);
    }
    __syncthreads();
    int deg = h[t];
    sc[t] = deg;
    __syncthreads();
    for (int off = 1; off < 256; off <<= 1) {
        int v = (t >= off) ? sc[t - off] : 0;
        __syncthreads();
        sc[t] += v;
        __syncthreads();
    }
    int excl = sc[t] - deg;
    cur[t] = excl;
    int node = b * 256 + t;
    if (node < N_NODES) {
        offs[node] = beg + excl;
        dinv[node] = rsqrtf((float)deg + 1.0f);  // +1 self-loop
    }
    __syncthreads();
    for (int j = beg + t; j < end; j += 256) {
        int2 p = binned[j];
        int pos = atomicAdd(&cur[p.y & 255], 1);
        csr[beg + pos] = p.x;
    }
}

// ---------------- W1 transpose -> bf16  [256][128] -> [128][256] ----------------
__global__ __launch_bounds__(256) void w1t_kernel(const float* __restrict__ W1,
                                                  ushort_t* __restrict__ W1T) {
    int t = blockIdx.x * 256 + threadIdx.x;  // 8192 threads
#pragma unroll
    for (int j = 0; j < 4; j++) {
        int e = j * 8192 + t;                // e = n*256 + k  (coalesced writes)
        int n = e >> 8, k = e & 255;
        W1T[e] = f2bf(W1[k * F_HID + n]);
    }
}

// ---------------- W2 transpose -> bf16  [128][32] -> [32][128] ----------------
__global__ __launch_bounds__(256) void w2t_kernel(const float* __restrict__ W2,
                                                  ushort_t* __restrict__ W2T) {
    int e = blockIdx.x * 256 + threadIdx.x;  // 4096 threads; e = n*128 + k
    int n = e >> 7, k = e & 127;
    W2T[e] = f2bf(W2[k * F_OUT + n]);
}

// ---------------- GEMM1 (MFMA): h0 = bf16(x @ W1)  [100000,256]x[256,128] ----------------
__global__ __launch_bounds__(256) void gemm1_kernel(const float* __restrict__ x,
                                                    const ushort_t* __restrict__ W1T,
                                                    ushort_t* __restrict__ h0bf) {
    __shared__ ushort_t Bst[F_HID][F_IN + 8];  // 128 x 264 bf16 = 66 KB
    const int tid = threadIdx.x;
    const int rbase = blockIdx.x * 64;
    const int w = tid >> 6;        // wave 0..3
    const int lane = tid & 63;
    const int q = lane >> 4;       // quad 0..3
    const int nloc = lane & 15;    // 0..15

    // stage W1T -> LDS (4096 x 16B, coalesced)
#pragma unroll
    for (int j = 0; j < 16; j++) {
        int f = j * 256 + tid;           // 0..4095
        int n = f >> 5, kg = f & 31;     // kg: 8-bf16 group
        uint4 v = ((const uint4*)(W1T + n * F_IN))[kg];
        *(uint4*)(&Bst[n][kg * 8]) = v;
    }
    __syncthreads();

    const int rowA = rbase + w * 16 + nloc;
    const bool okA = rowA < N_NODES;
    const float* ap = x + (size_t)rowA * F_IN + q * 8;

    floatx4 acc[8];
#pragma unroll
    for (int t = 0; t < 8; t++) acc[t] = (floatx4){0.f, 0.f, 0.f, 0.f};

#pragma unroll
    for (int k0 = 0; k0 < F_IN; k0 += 32) {
        float4 f0 = make_float4(0.f, 0.f, 0.f, 0.f);
        float4 f1 = make_float4(0.f, 0.f, 0.f, 0.f);
        if (okA) {
            f0 = *(const float4*)(ap + k0);
            f1 = *(const float4*)(ap + k0 + 4);
        }
        short8 a;
        a[0] = (short)f2bf(f0.x); a[1] = (short)f2bf(f0.y);
        a[2] = (short)f2bf(f0.z); a[3] = (short)f2bf(f0.w);
        a[4] = (short)f2bf(f1.x); a[5] = (short)f2bf(f1.y);
        a[6] = (short)f2bf(f1.z); a[7] = (short)f2bf(f1.w);
#pragma unroll
        for (int t = 0; t < 8; t++) {
            short8 b = *(const short8*)(&Bst[t * 16 + nloc][k0 + q * 8]);
            acc[t] = __builtin_amdgcn_mfma_f32_16x16x32_bf16(a, b, acc[t], 0, 0, 0);
        }
    }

    // D layout: col = lane&15 (n within tile), row = q*4 + reg
#pragma unroll
    for (int reg = 0; reg < 4; reg++) {
        int rowD = rbase + w * 16 + q * 4 + reg;
        if (rowD < N_NODES) {
            ushort_t* op = h0bf + (size_t)rowD * F_HID + nloc;
#pragma unroll
            for (int t = 0; t < 8; t++) op[t * 16] = f2bf(acc[t][reg]);
        }
    }
}

// ---------------- gather aggregation layer 1 (bf16 rows, fp32 acc, unroll-4) ----------------
__global__ __launch_bounds__(256) void gather128(const ushort_t* __restrict__ h0bf,
                                                 const int* __restrict__ offs,
                                                 const int* __restrict__ csr,
                                                 const float* __restrict__ dinv,
                                                 ushort_t* __restrict__ aggbf) {
    int node = blockIdx.x * 8 + (threadIdx.x >> 5);
    int l = threadIdx.x & 31;
    float dn = dinv[node];
    uint2 sv = ((const uint2*)(h0bf + (size_t)node * F_HID))[l];
    float s = dn * dn;
    float4 acc;
    acc.x = bf_lo(sv.x) * s; acc.y = bf_hi(sv.x) * s;
    acc.z = bf_lo(sv.y) * s; acc.w = bf_hi(sv.y) * s;

    int beg = offs[node], end = offs[node + 1];
    int j = beg;
    for (; j + 3 < end; j += 4) {
        int s0 = csr[j], s1 = csr[j + 1], s2 = csr[j + 2], s3 = csr[j + 3];
        float n0 = dinv[s0] * dn, n1 = dinv[s1] * dn;
        float n2 = dinv[s2] * dn, n3 = dinv[s3] * dn;
        uint2 v0 = ((const uint2*)(h0bf + (size_t)s0 * F_HID))[l];
        uint2 v1 = ((const uint2*)(h0bf + (size_t)s1 * F_HID))[l];
        uint2 v2 = ((const uint2*)(h0bf + (size_t)s2 * F_HID))[l];
        uint2 v3 = ((const uint2*)(h0bf + (size_t)s3 * F_HID))[l];
        acc.x += bf_lo(v0.x) * n0 + bf_lo(v1.x) * n1 + bf_lo(v2.x) * n2 + bf_lo(v3.x) * n3;
        acc.y += bf_hi(v0.x) * n0 + bf_hi(v1.x) * n1 + bf_hi(v2.x) * n2 + bf_hi(v3.x) * n3;
        acc.z += bf_lo(v0.y) * n0 + bf_lo(v1.y) * n1 + bf_lo(v2.y) * n2 + bf_lo(v3.y) * n3;
        acc.w += bf_hi(v0.y) * n0 + bf_hi(v1.y) * n1 + bf_hi(v2.y) * n2 + bf_hi(v3.y) * n3;
    }
    for (; j < end; j++) {
        int s0 = csr[j];
        float n0 = dinv[s0] * dn;
        uint2 v0 = ((const uint2*)(h0bf + (size_t)s0 * F_HID))[l];
        acc.x += bf_lo(v0.x) * n0; acc.y += bf_hi(v0.x) * n0;
        acc.z += bf_lo(v0.y) * n0; acc.w += bf_hi(v0.y) * n0;
    }
    uint2 p;
    p.x = (uint_t)f2bf(acc.x) | ((uint_t)f2bf(acc.y) << 16);
    p.y = (uint_t)f2bf(acc.z) | ((uint_t)f2bf(acc.w) << 16);
    ((uint2*)(aggbf + (size_t)node * F_HID))[l] = p;
}

// ---------------- GEMM2 (MFMA): h2 = bf16(relu(agg + b1) @ W2) ----------------
__global__ __launch_bounds__(256) void gemm2_kernel(const ushort_t* __restrict__ aggbf,
                                                    const float* __restrict__ b1,
                                                    const ushort_t* __restrict__ W2T,
                                                    ushort_t* __restrict__ h2bf) {
    __shared__ ushort_t Bs[F_OUT][F_HID + 8];  // 32 x 136 bf16 = 8.7 KB
    __shared__ float b1s[F_HID];
    const int tid = threadIdx.x;
    const int rbase = blockIdx.x * 64;
    const int w = tid >> 6;
    const int lane = tid & 63;
    const int q = lane >> 4;
    const int nloc = lane & 15;

    if (tid < F_HID) b1s[tid] = b1[tid];
    // stage W2T: 32 rows x 16 uint4 = 512, 2 per thread
#pragma unroll
    for (int jj = 0; jj < 2; jj++) {
        int f = jj * 256 + tid;       // 0..511
        int n = f >> 4, kg = f & 15;
        uint4 v = ((const uint4*)(W2T + n * F_HID))[kg];
        *(uint4*)(&Bs[n][kg * 8]) = v;
    }
    __syncthreads();

    const int rowA = rbase + w * 16 + nloc;
    const bool okA = rowA < N_NODES;

    floatx4 acc[2];
    acc[0] = (floatx4){0.f, 0.f, 0.f, 0.f};
    acc[1] = (floatx4){0.f, 0.f, 0.f, 0.f};

#pragma unroll
    for (int k0 = 0; k0 < F_HID; k0 += 32) {
        int kk = k0 + q * 8;
        uint4 av = make_uint4(0, 0, 0, 0);
        if (okA) av = *(const uint4*)(aggbf + (size_t)rowA * F_HID + kk);
        float4 bb0 = *(const float4*)(&b1s[kk]);
        float4 bb1 = *(const float4*)(&b1s[kk + 4]);
        short8 a;
        a[0] = (short)f2bf(fmaxf(bf_lo(av.x) + bb0.x, 0.f));
        a[1] = (short)f2bf(fmaxf(bf_hi(av.x) + bb0.y, 0.f));
        a[2] = (short)f2bf(fmaxf(bf_lo(av.y) + bb0.z, 0.f));
        a[3] = (short)f2bf(fmaxf(bf_hi(av.y) + bb0.w, 0.f));
        a[4] = (short)f2bf(fmaxf(bf_lo(av.z) + bb1.x, 0.f));
        a[5] = (short)f2bf(fmaxf(bf_hi(av.z) + bb1.y, 0.f));
        a[6] = (short)f2bf(fmaxf(bf_lo(av.w) + bb1.z, 0.f));
        a[7] = (short)f2bf(fmaxf(bf_hi(av.w) + bb1.w, 0.f));
#pragma unroll
        for (int t = 0; t < 2; t++) {
            short8 b = *(const short8*)(&Bs[t * 16 + nloc][kk]);
            acc[t] = __builtin_amdgcn_mfma_f32_16x16x32_bf16(a, b, acc[t], 0, 0, 0);
        }
    }
#pragma unroll
    for (int reg = 0; reg < 4; reg++) {
        int rowD = rbase + w * 16 + q * 4 + reg;
        if (rowD < N_NODES) {
            ushort_t* op = h2bf + (size_t)rowD * F_OUT + nloc;
            op[0]  = f2bf(acc[0][reg]);
            op[16] = f2bf(acc[1][reg]);
        }
    }
}

// ---------------- gather aggregation layer 2 + bias + log_softmax ----------------
__global__ __launch_bounds__(256) void gather32_lsm(const ushort_t* __restrict__ h2bf,
                                                    const int* __restrict__ offs,
                                                    const int* __restrict__ csr,
                                                    const float* __restrict__ dinv,
                                                    const float* __restrict__ b2,
                                                    float* __restrict__ out) {
    int node = blockIdx.x * 32 + (threadIdx.x >> 3);
    int l = threadIdx.x & 7;
    float dn = dinv[node];
    uint2 sv = ((const uint2*)(h2bf + (size_t)node * F_OUT))[l];
    float s = dn * dn;
    float4 acc;
    acc.x = bf_lo(sv.x) * s; acc.y = bf_hi(sv.x) * s;
    acc.z = bf_lo(sv.y) * s; acc.w = bf_hi(sv.y) * s;

    int beg = offs[node], end = offs[node + 1];
    int j = beg;
    for (; j + 3 < end; j += 4) {
        int s0 = csr[j], s1 = csr[j + 1], s2 = csr[j + 2], s3 = csr[j + 3];
        float n0 = dinv[s0] * dn, n1 = dinv[s1] * dn;
        float n2 = dinv[s2] * dn, n3 = dinv[s3] * dn;
        uint2 v0 = ((const uint2*)(h2bf + (size_t)s0 * F_OUT))[l];
        uint2 v1 = ((const uint2*)(h2bf + (size_t)s1 * F_OUT))[l];
        uint2 v2 = ((const uint2*)(h2bf + (size_t)s2 * F_OUT))[l];
        uint2 v3 = ((const uint2*)(h2bf + (size_t)s3 * F_OUT))[l];
        acc.x += bf_lo(v0.x) * n0 + bf_lo(v1.x) * n1 + bf_lo(v2.x) * n2 + bf_lo(v3.x) * n3;
        acc.y += bf_hi(v0.x) * n0 + bf_hi(v1.x) * n1 + bf_hi(v2.x) * n2 + bf_hi(v3.x) * n3;
        acc.z += bf_lo(v0.y) * n0 + bf_lo(v1.y) * n1 + bf_lo(v2.y) * n2 + bf_lo(v3.y) * n3;
        acc.w += bf_hi(v0.y) * n0 + bf_hi(v1.y) * n1 + bf_hi(v2.y) * n2 + bf_hi(v3.y) * n3;
    }
    for (; j < end; j++) {
        int s0 = csr[j];
        float n0 = dinv[s0] * dn;
        uint2 v0 = ((const uint2*)(h2bf + (size_t)s0 * F_OUT))[l];
        acc.x += bf_lo(v0.x) * n0; acc.y += bf_hi(v0.x) * n0;
        acc.z += bf_lo(v0.y) * n0; acc.w += bf_hi(v0.y) * n0;
    }
    float4 bb = ((const float4*)b2)[l];
    acc.x += bb.x; acc.y += bb.y; acc.z += bb.z; acc.w += bb.w;

    float m = fmaxf(fmaxf(acc.x, acc.y), fmaxf(acc.z, acc.w));
#pragma unroll
    for (int off = 1; off < 8; off <<= 1) m = fmaxf(m, __shfl_xor(m, off, 8));
    float es = __expf(acc.x - m) + __expf(acc.y - m) + __expf(acc.z - m) + __expf(acc.w - m);
#pragma unroll
    for (int off = 1; off < 8; off <<= 1) es += __shfl_xor(es, off, 8);
    float lse = m + __logf(es);
    float4 o = make_float4(acc.x - lse, acc.y - lse, acc.z - lse, acc.w - lse);
    ((float4*)(out + (size_t)node * F_OUT))[l] = o;
}

extern "C" void kernel_launch(void* const* d_in, const int* in_sizes, int n_in,
                              void* d_out, int out_size, void* d_ws, size_t ws_size,
                              hipStream_t stream) {
    const float* x  = (const float*)d_in[0];
    const int*   ei = (const int*)d_in[1];
    const float* W1 = (const float*)d_in[2];
    const float* b1 = (const float*)d_in[3];
    const float* W2 = (const float*)d_in[4];
    const float* b2 = (const float*)d_in[5];
    float* out = (float*)d_out;

    // workspace layout (4B units)
    float* ws = (float*)d_ws;
    float*    dinv          = ws;                      // 100096
    int*      offs          = (int*)(ws + 100096);     // 100128
    int*      bucket_cnt    = (int*)(ws + 200224);     // 512
    int*      bucket_base   = (int*)(ws + 200736);     // 512
    int*      bucket_cursor = (int*)(ws + 201248);     // 512
    int*      csr           = (int*)(ws + 201760);     // 1,600,000
    ushort_t* W1T           = (ushort_t*)(ws + 1801760);   // 32768 ushort = 16384 floats
    ushort_t* W2T           = (ushort_t*)(ws + 1818144);   // 4096 ushort = 2048 floats
    ushort_t* h0bf          = (ushort_t*)(ws + 1820192);   // 12.8M ushort = 6.4M floats
    ushort_t* aggbf         = (ushort_t*)(ws + 8220192);   // 12.8M ushort = 6.4M floats
    ushort_t* h2bf          = (ushort_t*)(ws + 14620192);  // 3.2M ushort = 1.6M floats
    int2*     binned        = (int2*)aggbf;                // alias: dead before gather128 writes agg

    hipMemsetAsync(bucket_cnt, 0, 512 * sizeof(int), stream);
    hist_kernel<<<BIN_BLOCKS, 256, 0, stream>>>(ei, bucket_cnt);
    scan_kernel<<<1, 512, 0, stream>>>(bucket_cnt, bucket_base, bucket_cursor, offs);
    bin_kernel<<<BIN_BLOCKS, 256, 0, stream>>>(ei, bucket_cursor, binned);
    build_kernel<<<NBUCK, 256, 0, stream>>>(binned, bucket_base, offs, csr, dinv);
    w1t_kernel<<<32, 256, 0, stream>>>(W1, W1T);
    w2t_kernel<<<16, 256, 0, stream>>>(W2, W2T);
    gemm1_kernel<<<(N_NODES + 63) / 64, 256, 0, stream>>>(x, W1T, h0bf);
    gather128<<<N_NODES / 8, 256, 0, stream>>>(h0bf, offs, csr, dinv, aggbf);
    gemm2_kernel<<<(N_NODES + 63) / 64, 256, 0, stream>>>(aggbf, b1, W2T, h2bf);
    gather32_lsm<<<N_NODES / 32, 256, 0, stream>>>(h2bf, offs, csr, dinv, b2, out);
}